// Round 7
// baseline (1087.275 us; speedup 1.0000x reference)
//
#include <hip/hip_runtime.h>
#include <stdint.h>

typedef unsigned short u16;
typedef unsigned int u32;
typedef __attribute__((ext_vector_type(8))) short short8;
typedef __attribute__((ext_vector_type(4))) float f32x4;
typedef __attribute__((ext_vector_type(4))) u32 u32x4;

#define B_ 8
#define N_ 8192
#define M_ 2048
#define DD 256
#define KENC 32

// consts layout (float offsets)
#define SC1 0
#define SH1 256
#define SC2 512
#define SH2 768
#define C2OFF 1024
#define SOFF 1056
#define RNOFF 1088

// ws offsets (bytes)
#define OFF_IDX3   0ull
#define OFF_W3     786432ull
#define OFF_FT     1572864ull
#define OFF_H1T    68681728ull     // Epart aliases this region after GEMM2 (1024 slabs x 8192 f32)
#define OFF_ERELU  102236160ull
#define OFF_PART   102498304ull
#define OFF_CONSTS 102760448ull
#define OFF_CTX    102768640ull
#define OFF_W1D    102776832ull
#define OFF_W2D    103038976ull
#define OFF_CWD    103170048ull
#define OFF_FLAG   103186432ull
// k1 MFMA fragments live in the (pre-k2) dead Ft region
#define OFF_QF     OFF_FT
#define OFF_PF     (OFF_FT + 4194304ull)

#define LCAP 16

__device__ __forceinline__ float bf2f(u16 v){ return __uint_as_float(((u32)v)<<16); }
__device__ __forceinline__ u16 f2bf(float f){
  u32 x = __float_as_uint(f);
  return (u16)((x + 0x7FFFu + ((x>>16)&1u)) >> 16);
}
__device__ __forceinline__ float ldf(const void* p, size_t i, int f){
  return f ? ((const float*)p)[i] : bf2f(((const u16*)p)[i]);
}
// async 16B global->LDS (wave-uniform lds base + lane*16)
__device__ __forceinline__ void gl_lds16(const u16* g, u16* l){
  __builtin_amdgcn_global_load_lds(
      (const __attribute__((address_space(1))) void*)g,
      (__attribute__((address_space(3))) void*)l, 16, 0, 0);
}

// ---------------- D: runtime dtype detection from bn_v1 (uniform(0.5,1.5)) ----------------
__global__ __launch_bounds__(256) void k_detect(const void* v1, int* flagp){
  __shared__ int cntb, cntf;
  int t = threadIdx.x;
  if (t==0){ cntb=0; cntf=0; ((u32*)flagp)[1] = 0u; }  // [1] = coord-max accumulator
  __syncthreads();
  float vb = bf2f(((const u16*)v1)[t]);
  if (!(vb > 0.4f && vb < 1.6f)) atomicAdd(&cntb, 1);
  if (t < 64){
    float vf = ((const float*)v1)[t];
    if (!(vf > 0.4f && vf < 1.6f)) atomicAdd(&cntf, 1);
  }
  __syncthreads();
  if (t==0) flagp[0] = (cntb > 0 && cntf == 0) ? 1 : 0;
}

// ---------------- C: convert w1/w2/cw to bf16 ws copies ----------------
__global__ __launch_bounds__(256) void k_convert(
    const void* w1, const void* w2, const void* cwsrc, const int* __restrict__ flagp,
    u16* __restrict__ W1d, u16* __restrict__ W2d, u16* __restrict__ CWd){
  int id = blockIdx.x*256 + threadIdx.x;
  int f = flagp[0];
  if (id < 131072){
    W1d[id] = f ? f2bf(((const float*)w1)[id]) : ((const u16*)w1)[id];
  } else if (id < 196608){
    int j = id - 131072;
    W2d[j] = f ? f2bf(((const float*)w2)[j]) : ((const u16*)w2)[j];
  } else if (id < 204800){
    int j = id - 196608;
    CWd[j] = f ? f2bf(((const float*)cwsrc)[j]) : ((const u16*)cwsrc)[j];
  }
}

// ---------------- K_FRAG: build MFMA distance fragments ----------------
// K-slot layout (32): s = dim*9 + a*3 + bb (a,bb in {h,m,l}): A = -2*u_a[dim], B = k_bb[dim]
// (3-way bf16 split is EXACT: fp32 24-bit mantissa = 8+8+8). slots 27,28: A=x2h,x2l B=1;
// slots 29,30: A=1 B=y2h,y2l; slot 31 = 0. MFMA acc = d_hat = x2+y2-2*dot with
// |d_hat - d_exact| <= C^2*2^-13.3 (fp32 accum + x2/y2 2-split only; coords exact).
__global__ __launch_bounds__(256) void k_frag(
    const void* unknown, const void* known, const int* __restrict__ flagp,
    u16* __restrict__ Qf, u16* __restrict__ Pf, u32* __restrict__ cmaxp){
  __shared__ float mred[256];
  int id = blockIdx.x*256 + threadIdx.x;
  int t = threadIdx.x;
  int f = flagp[0];
  float mx = 0.f;
  u16 S[32];
  if (id < 81920){
    int isq = id < 65536;
    int b, row; size_t o;
    if (isq){ b = id >> 13; row = id & 8191; o = ((size_t)b*N_ + row)*3; }
    else { int j = id - 65536; b = j >> 11; row = j & 2047; o = ((size_t)b*M_ + row)*3; }
    float x = ldf(isq?unknown:known, o, f);
    float y = ldf(isq?unknown:known, o+1, f);
    float z = ldf(isq?unknown:known, o+2, f);
    mx = fmaxf(fmaxf(fabsf(x),fabsf(y)),fabsf(z));
    float s2 = __fadd_rn(__fadd_rn(__fmul_rn(x,x), __fmul_rn(y,y)), __fmul_rn(z,z));
    float c[3] = {x,y,z};
    #pragma unroll
    for (int d3=0; d3<3; d3++){
      float u = c[d3];
      u16 h = f2bf(u);  float r1 = __fsub_rn(u, bf2f(h));     // exact (Sterbenz)
      u16 m2 = f2bf(r1); float r2 = __fsub_rn(r1, bf2f(m2));  // exact
      u16 l2 = f2bf(r2);                                       // exact (<=8 bits left)
      u16 sv[3];
      if (isq){
        sv[0] = f2bf(-2.f*bf2f(h));   // -2*bf16 is exact in bf16
        sv[1] = f2bf(-2.f*bf2f(m2));
        sv[2] = f2bf(-2.f*bf2f(l2));
        #pragma unroll
        for (int a=0; a<3; a++)
          #pragma unroll
          for (int bb=0; bb<3; bb++) S[d3*9 + a*3 + bb] = sv[a];
      } else {
        sv[0] = h; sv[1] = m2; sv[2] = l2;
        #pragma unroll
        for (int a=0; a<3; a++)
          #pragma unroll
          for (int bb=0; bb<3; bb++) S[d3*9 + a*3 + bb] = sv[bb];
      }
    }
    u16 s2h = f2bf(s2); u16 s2l = f2bf(__fsub_rn(s2, bf2f(s2h)));
    if (isq){ S[27]=s2h; S[28]=s2l; S[29]=0x3F80; S[30]=0x3F80; }
    else    { S[27]=0x3F80; S[28]=0x3F80; S[29]=s2h; S[30]=s2l; }
    S[31] = 0;
    u16* dst = isq ? (Qf + ((size_t)(b*512 + (row>>4))*512) + (row&15)*8)
                   : (Pf + ((size_t)(b*128 + (row>>4))*512) + (row&15)*8);
    #pragma unroll
    for (int qd=0; qd<4; qd++){
      u32x4 w;
      #pragma unroll
      for (int q=0; q<4; q++) w[q] = (u32)S[qd*8+q*2] | ((u32)S[qd*8+q*2+1]<<16);
      *(u32x4*)(dst + qd*128) = w;
    }
  }
  mred[t] = mx; __syncthreads();
  for (int w=128; w>0; w>>=1){ if (t<w) mred[t] = fmaxf(mred[t], mred[t+w]); __syncthreads(); }
  if (t==0) atomicMax(cmaxp, __float_as_uint(mred[0]));   // positive floats: uint-monotone
}

// ---------------- K0: fold BN params, codeword norms ----------------
__global__ __launch_bounds__(256) void k0_setup(
    const void* cb1, const void* g1, const void* be1, const void* m1, const void* v1,
    const void* cb2, const void* g2, const void* be2, const void* m2, const void* v2,
    const u16* __restrict__ CWd, const void* es, const int* __restrict__ flagp,
    float* __restrict__ consts){
  int t = threadIdx.x;
  int f = flagp[0];
  {
    float g = ldf(g1,t,f), be = ldf(be1,t,f), m = ldf(m1,t,f), v = ldf(v1,t,f), cb = ldf(cb1,t,f);
    float r = 1.f/sqrtf(v + 1e-5f);
    float sc = g*r;
    consts[SC1+t] = sc; consts[SH1+t] = (cb-m)*sc + be;
  }
  {
    float g = ldf(g2,t,f), be = ldf(be2,t,f), m = ldf(m2,t,f), v = ldf(v2,t,f), cb = ldf(cb2,t,f);
    float r = 1.f/sqrtf(v + 1e-5f);
    float sc = g*r;
    consts[SC2+t] = sc; consts[SH2+t] = (cb-m)*sc + be;
  }
  if (t < KENC){
    float s = 0.f;
    for (int d=0; d<DD; d++){ float c = bf2f(CWd[t*DD+d]); s = fmaf(c,c,s); }
    consts[C2OFF+t] = s;
    consts[SOFF+t]  = ldf(es,t,f);
  }
}

// ---------------- K1: three_nn via MFMA filter + exact recovery (LDS-staged) ----------------
// Round-5-verified selection machinery; data path: Pf staged through LDS in 32KB
// chunks (32 tiles = 16384 u16) via global_load_lds DMA, reads are linear ds_read_b128.
// ROUND-6 BUG FIXED: chunk = 32 tiles = 16384 u16 (32KB), so PB must be [16384] and
// staging needs 32 shots (i<8); round 6 had PB[8192]/i<4 -> tiles 16..31 of every
// chunk were read from out-of-bounds LDS garbage.
__global__ __launch_bounds__(256) void k1_three_nn(
    const void* unknown, const void* known, const int* __restrict__ flagp,
    const u16* __restrict__ Qf, const u16* __restrict__ Pf,
    const u32* __restrict__ cmaxp,
    int* __restrict__ idx3, float* __restrict__ w3){
  __shared__ u16 PB[16384];       // 32KB: 32 P-tiles of 512 u16
  __shared__ int lists[64*LCAP];  // 4KB
  __shared__ int lcount[64];
  int b = blockIdx.y, t = threadIdx.x;
  int f = flagp[0];
  if (t < 64) lcount[t] = 0;
  int wave = t>>6, lane = t&63, ln = lane&15, quad = lane>>4;
  int qt = blockIdx.x*4 + wave;
  short8 bq = *(const short8*)(Qf + ((size_t)(b*512 + qt)*512) + lane*8);
  const u16* Pfb = Pf + (size_t)b*65536;
  float C = __uint_as_float(cmaxp[0]);
  float delta = C*C*(1.0f/2048.f);
  // ---- pass 1: 3 smallest d_hat values (two independent chains: even/odd tiles) ----
  float a0=3.4e38f, a1=3.4e38f, a2=3.4e38f;
  float c0=3.4e38f, c1=3.4e38f, c2=3.4e38f;
  for (int ch=0; ch<4; ch++){
    #pragma unroll
    for (int i=0;i<8;i++)
      gl_lds16(Pfb + ch*16384 + i*2048 + wave*512 + lane*8, PB + i*2048 + wave*512);
    __syncthreads();   // drains vmcnt (DMA) before reads
    for (int j=0; j<32; j+=2){
      short8 p0 = *(const short8*)(PB + j*512 + lane*8);
      short8 p1 = *(const short8*)(PB + j*512 + 512 + lane*8);
      f32x4 dA = __builtin_amdgcn_mfma_f32_16x16x32_bf16(p0, bq, (f32x4)0.f, 0,0,0);
      f32x4 dB = __builtin_amdgcn_mfma_f32_16x16x32_bf16(p1, bq, (f32x4)0.f, 0,0,0);
      #pragma unroll
      for (int r=0; r<4; r++){
        float dx = dA[r];
        float t0=fminf(a0,dx), t1=__builtin_amdgcn_fmed3f(a0,a1,dx), t2=__builtin_amdgcn_fmed3f(a1,a2,dx);
        a0=t0; a1=t1; a2=t2;
        float dy = dB[r];
        float s0=fminf(c0,dy), s1=__builtin_amdgcn_fmed3f(c0,c1,dy), s2=__builtin_amdgcn_fmed3f(c1,c2,dy);
        c0=s0; c1=s1; c2=s2;
      }
    }
    __syncthreads();   // chunk fully consumed before restage
  }
  { // merge odd chain into even chain
    float dv3[3] = {c0,c1,c2};
    #pragma unroll
    for (int e=0; e<3; e++){
      float dx = dv3[e];
      float t0=fminf(a0,dx), t1=__builtin_amdgcn_fmed3f(a0,a1,dx), t2=__builtin_amdgcn_fmed3f(a1,a2,dx);
      a0=t0; a1=t1; a2=t2;
    }
  }
  #pragma unroll
  for (int st=16; st<64; st<<=1){   // merge across the 4 quad-lanes of each query
    float o0=__shfl_xor(a0,st,64), o1=__shfl_xor(a1,st,64), o2=__shfl_xor(a2,st,64);
    float dv3[3] = {o0,o1,o2};
    #pragma unroll
    for (int e=0; e<3; e++){
      float dx = dv3[e];
      float t0=fminf(a0,dx), t1=__builtin_amdgcn_fmed3f(a0,a1,dx), t2=__builtin_amdgcn_fmed3f(a1,a2,dx);
      a0=t0; a1=t1; a2=t2;
    }
  }
  float TT = a2 + 2.f*delta;
  // ---- pass 2: collect candidate indices (restaged chunks) ----
  int lq = wave*16 + ln;
  for (int ch=0; ch<4; ch++){
    #pragma unroll
    for (int i=0;i<8;i++)
      gl_lds16(Pfb + ch*16384 + i*2048 + wave*512 + lane*8, PB + i*2048 + wave*512);
    __syncthreads();
    for (int j=0; j<32; j++){
      short8 ap = *(const short8*)(PB + j*512 + lane*8);
      f32x4 dv = __builtin_amdgcn_mfma_f32_16x16x32_bf16(ap, bq, (f32x4)0.f, 0,0,0);
      if (__builtin_expect(dv[0]<=TT || dv[1]<=TT || dv[2]<=TT || dv[3]<=TT, 0)){
        #pragma unroll
        for (int r=0; r<4; r++){
          if (dv[r] <= TT){
            int m = (ch*32+j)*16 + quad*4 + r;
            int ix = atomicAdd(&lcount[lq], 1);
            if (ix < LCAP) lists[lq*LCAP + ix] = m;
          }
        }
      }
    }
    __syncthreads();
  }
  // ---- final: exact distances on the candidate list, stable lex top-3 ----
  if (quad == 0){
    int pid = blockIdx.x*64 + wave*16 + ln;
    size_t uo = ((size_t)b*N_ + pid)*3;
    float ux=ldf(unknown,uo,f), uy=ldf(unknown,uo+1,f), uz=ldf(unknown,uo+2,f);
    float x2 = __fadd_rn(__fadd_rn(__fmul_rn(ux,ux), __fmul_rn(uy,uy)), __fmul_rn(uz,uz));
    // pre-doubled coords: fl(2a*b)=2*fl(a*b), fl(2s+2t)=2*fl(s+t) -> bit-exact vs reference
    float u2x=ux+ux, u2y=uy+uy, u2z=uz+uz;
    float e0=3.4e38f, e1=3.4e38f, e2=3.4e38f;
    int i0=0x7fffffff, i1=0x7fffffff, i2=0x7fffffff;
    int cnt = lcount[lq];
    int lim = (cnt <= LCAP) ? cnt : 0;
    for (int ii=0; ii<lim; ii++){
      int m = lists[lq*LCAP + ii];
      size_t o = ((size_t)b*M_ + m)*3;
      float kx=ldf(known,o,f), ky=ldf(known,o+1,f), kz=ldf(known,o+2,f);
      float y2 = __fadd_rn(__fadd_rn(__fmul_rn(kx,kx), __fmul_rn(ky,ky)), __fmul_rn(kz,kz));
      float dot2 = __fadd_rn(__fadd_rn(__fmul_rn(u2x,kx), __fmul_rn(u2y,ky)), __fmul_rn(u2z,kz));
      float dd = __fadd_rn(__fsub_rn(x2, dot2), y2);
      bool lt0 = (dd < e0) || (dd == e0 && m < i0);
      bool lt1 = (dd < e1) || (dd == e1 && m < i1);
      bool lt2 = (dd < e2) || (dd == e2 && m < i2);
      if (lt0){ e2=e1;i2=i1; e1=e0;i1=i0; e0=dd;i0=m; }
      else if (lt1){ e2=e1;i2=i1; e1=dd;i1=m; }
      else if (lt2){ e2=dd; i2=m; }
    }
    if (cnt > LCAP){  // overflow fallback: exact full scan (never on sane data)
      for (int m=0; m<M_; m++){
        size_t o = ((size_t)b*M_ + m)*3;
        float kx=ldf(known,o,f), ky=ldf(known,o+1,f), kz=ldf(known,o+2,f);
        float y2 = __fadd_rn(__fadd_rn(__fmul_rn(kx,kx), __fmul_rn(ky,ky)), __fmul_rn(kz,kz));
        float dot2 = __fadd_rn(__fadd_rn(__fmul_rn(u2x,kx), __fmul_rn(u2y,ky)), __fmul_rn(u2z,kz));
        float dd = __fadd_rn(__fsub_rn(x2, dot2), y2);
        bool lt0 = (dd < e0) || (dd == e0 && m < i0);
        bool lt1 = (dd < e1) || (dd == e1 && m < i1);
        bool lt2 = (dd < e2) || (dd == e2 && m < i2);
        if (lt0){ e2=e1;i2=i1; e1=e0;i1=i0; e0=dd;i0=m; }
        else if (lt1){ e2=e1;i2=i1; e1=dd;i1=m; }
        else if (lt2){ e2=dd; i2=m; }
      }
    }
    float da = __fsqrt_rn(fmaxf(e0,1e-12f));
    float db = __fsqrt_rn(fmaxf(e1,1e-12f));
    float dc = __fsqrt_rn(fmaxf(e2,1e-12f));
    float r0 = __fdiv_rn(1.f, __fadd_rn(da,1e-8f));
    float r1 = __fdiv_rn(1.f, __fadd_rn(db,1e-8f));
    float r2 = __fdiv_rn(1.f, __fadd_rn(dc,1e-8f));
    float rs = __fadd_rn(__fadd_rn(r0,r1),r2);
    size_t o = ((size_t)b*N_ + pid)*3;
    idx3[o]=i0; idx3[o+1]=i1; idx3[o+2]=i2;
    w3[o]=__fdiv_rn(r0,rs); w3[o+1]=__fdiv_rn(r1,rs); w3[o+2]=__fdiv_rn(r2,rs);
  }
}

// ---------------- K2: three_interpolate -> Ft[:, :, 0:256] (point-major) ----------------
__global__ __launch_bounds__(256) void k2_interp(
    const void* kf, const int* __restrict__ idx3,
    const float* __restrict__ w3, const int* __restrict__ flagp, u16* __restrict__ Ft){
  __shared__ u16 Ls[M_*8]; // [i][c], 32KB
  int ct = blockIdx.x;  // 0..31 (channel tile of 8)
  int rg = blockIdx.y;  // 0..3 (rep group)
  int b = blockIdx.z, t = threadIdx.x;
  int f = flagp[0];
  for (int cp=0; cp<4; cp++){
    int c0 = ct*8 + cp*2;
    size_t base0 = ((size_t)b*DD + c0)*M_;
    size_t base1 = base0 + M_;
    for (int i=t; i<M_; i+=256){
      float f0 = ldf(kf, base0+i, f);
      float f1 = ldf(kf, base1+i, f);
      u32 w = (u32)f2bf(f0) | ((u32)f2bf(f1)<<16);
      *(u32*)(Ls + i*8 + cp*2) = w;
    }
  }
  __syncthreads();
  for (int rep=rg*8; rep<rg*8+8; rep++){
    int pid = rep*256 + t;
    size_t o3 = ((size_t)b*N_ + pid)*3;
    int ia = idx3[o3], ib = idx3[o3+1], ic = idx3[o3+2];
    float wa = w3[o3], wb = w3[o3+1], wc = w3[o3+2];
    short8 va = *(const short8*)(Ls + ia*8);
    short8 vb = *(const short8*)(Ls + ib*8);
    short8 vc = *(const short8*)(Ls + ic*8);
    u32x4 pk;
    #pragma unroll
    for (int cq=0; cq<4; cq++){
      float fa0 = bf2f((u16)va[cq*2]),   fb0 = bf2f((u16)vb[cq*2]),   fc0 = bf2f((u16)vc[cq*2]);
      float fa1 = bf2f((u16)va[cq*2+1]), fb1 = bf2f((u16)vb[cq*2+1]), fc1 = bf2f((u16)vc[cq*2+1]);
      float v0 = fmaf(wc, fc0, fmaf(wb, fb0, wa*fa0));
      float v1 = fmaf(wc, fc1, fmaf(wb, fb1, wa*fa1));
      pk[cq] = (u32)f2bf(v0) | ((u32)f2bf(v1)<<16);
    }
    *(u32x4*)(Ft + ((size_t)b*N_ + pid)*512 + ct*8) = pk;
  }
}

// ---------------- K2b: transpose unknow_feats -> Ft[:, :, 256:512] ----------------
__global__ __launch_bounds__(256) void k2b_transpose_uf(
    const void* uf, const int* __restrict__ flagp, u16* __restrict__ Ft){
  __shared__ u16 Ls[64*72];
  int bx = blockIdx.x, cy = blockIdx.y, b = blockIdx.z, t = threadIdx.x;
  int f = flagp[0];
  {
    int n = t & 63, cg = t >> 6;
    for (int i=0; i<16; i++){
      int c = cg*16 + i;
      Ls[n*72 + c] = f2bf(ldf(uf, ((size_t)b*DD + cy*64 + c)*N_ + bx*64 + n, f));
    }
  }
  __syncthreads();
  int nl = t>>2, cc = t&3;
  u16* dst = Ft + ((size_t)b*N_ + bx*64 + nl)*512 + 256 + cy*64 + cc*16;
  *(u32x4*)dst     = *(const u32x4*)(Ls + nl*72 + cc*16);
  *(u32x4*)(dst+8) = *(const u32x4*)(Ls + nl*72 + cc*16 + 8);
}

// ---------------- K3/K4: MFMA GEMM, BK=64, global_load_lds + XOR-swizzled LDS ----------------
__global__ __launch_bounds__(256) void gemm_bn_relu(
    const u16* __restrict__ W, const u16* __restrict__ Fin,
    const float* __restrict__ consts, int sc_off, int sh_off,
    u16* __restrict__ Out, int K){
  __shared__ u16 SM[17408]; // As(8192)+Bs(8192) u16 in K-loop; Cs(128x136) in epilogue
  u16* As = SM; u16* Bs = SM + 8192;
  int b = blockIdx.z, ot = blockIdx.y*128, nt = blockIdx.x*128;
  int t = threadIdx.x, wave = t>>6, lane = t&63, ln = lane&15, quad = lane>>4;
  int wo = (wave&1)*64, wn = (wave>>1)*64;
  f32x4 acc[4][4];
  #pragma unroll
  for (int i=0;i<4;i++)
    #pragma unroll
    for (int j=0;j<4;j++) acc[i][j] = (f32x4)0.f;
  const u16* Wp = W + (size_t)ot*K;
  const u16* Fp = Fin + ((size_t)b*N_ + nt)*K;
  for (int kk=0; kk<K; kk+=64){
    #pragma unroll
    for (int i=0;i<4;i++){
      int c = wave*256 + i*64 + lane;          // chunk slot 0..1023
      int r = c>>3, k8 = (c&7) ^ (r&7);
      const u16* gA = Wp + (size_t)r*K + kk + k8*8;
      const u16* gB = Fp + (size_t)r*K + kk + k8*8;
      gl_lds16(gA, As + (size_t)(wave*256 + i*64)*8);
      gl_lds16(gB, Bs + (size_t)(wave*256 + i*64)*8);
    }
    __syncthreads();
    #pragma unroll
    for (int kh=0; kh<2; kh++){
      short8 af[4], bfr[4];
      #pragma unroll
      for (int i=0;i<4;i++){
        int R = wo + i*16 + ln, C = kh*4 + quad;
        af[i] = *(const short8*)(As + (size_t)(R*8 + (C^(R&7)))*8);
      }
      #pragma unroll
      for (int j=0;j<4;j++){
        int R = wn + j*16 + ln, C = kh*4 + quad;
        bfr[j] = *(const short8*)(Bs + (size_t)(R*8 + (C^(R&7)))*8);
      }
      #pragma unroll
      for (int i=0;i<4;i++)
        #pragma unroll
        for (int j=0;j<4;j++)
          acc[i][j] = __builtin_amdgcn_mfma_f32_16x16x32_bf16(af[i], bfr[j], acc[i][j], 0,0,0);
    }
    __syncthreads();
  }
  u16* Cs = SM; // stride 136
  #pragma unroll
  for (int i=0;i<4;i++){
    #pragma unroll
    for (int r=0;r<4;r++){
      int ol = wo + i*16 + quad*4 + r;
      float sc = consts[sc_off + ot + ol], sh = consts[sh_off + ot + ol];
      #pragma unroll
      for (int j=0;j<4;j++){
        float v = fmaxf(fmaf(acc[i][j][r], sc, sh), 0.f);
        Cs[(wn + j*16 + ln)*136 + ol] = f2bf(v);
      }
    }
  }
  __syncthreads();
  int nl = t>>1, half = t&1;
  u16* dst = Out + ((size_t)b*N_ + nt + nl)*256 + ot + half*64;
  const u16* srcr = Cs + nl*136 + half*64;
  #pragma unroll
  for (int c=0;c<8;c++)
    *(u32x4*)(dst + c*8) = *(const u32x4*)(srcr + c*8);
}

// ---------------- K5: encoding partials ----------------
__global__ __launch_bounds__(256, 6) void k5_enc_partial(
    const u16* __restrict__ X, const u16* __restrict__ cw,
    const float* __restrict__ consts, float* __restrict__ Epart,
    float* __restrict__ Asum){
  __shared__ u16 Xs[64*256];      // 32KB, swizzled
  __shared__ float A_lds[64*32];  // 8KB
  int g = blockIdx.x, b = blockIdx.y, t = threadIdx.x;
  int wave = t>>6, lane = t&63, ln = lane&15, quad = lane>>4;
  int ka = lane>>1, h = lane&1;          // accumulation roles: k index, d-half
  int dbase = wave*64 + h*32;            // 32 consecutive d per thread
  float c2v0 = consts[C2OFF + ln], c2v1 = consts[C2OFF + 16 + ln];
  float sv0  = consts[SOFF + ln],  sv1  = consts[SOFF + 16 + ln];
  int n0 = g*64;
  const u16* Xp = X + ((size_t)b*N_ + n0)*256;
  #pragma unroll
  for (int i=0;i<8;i++){
    int ch = t + i*256;
    int r = ch>>5, cc = ch&31;
    *(u32x4*)(Xs + r*256 + ((cc ^ (r&15))<<3)) = *(const u32x4*)(Xp + r*256 + cc*8);
  }
  __syncthreads();
  float xnf;
  {
    int row = t>>2, part = t&3;
    float s = 0.f;
    #pragma unroll
    for (int j=0;j<8;j++){
      int cc = part*8 + j;
      short8 xv = *(const short8*)(Xs + row*256 + ((cc ^ (row&15))<<3));
      #pragma unroll
      for (int q=0;q<8;q++){ float x = bf2f((u16)xv[q]); s = fmaf(x,x,s); }
    }
    s += __shfl_xor(s,1,64);
    s += __shfl_xor(s,2,64);
    xnf = s;
  }
  f32x4 pj0 = (f32x4)0.f, pj1 = (f32x4)0.f;
  {
    int row = wave*16 + ln;
    #pragma unroll
    for (int kk=0; kk<256; kk+=32){
      int cc = (kk>>3) + quad;
      short8 a   = *(const short8*)(Xs + row*256 + ((cc ^ (row&15))<<3));
      short8 bf0 = *(const short8*)(cw + (size_t)ln*256 + kk + quad*8);
      short8 bf1 = *(const short8*)(cw + (size_t)(16+ln)*256 + kk + quad*8);
      pj0 = __builtin_amdgcn_mfma_f32_16x16x32_bf16(a, bf0, pj0, 0,0,0);
      pj1 = __builtin_amdgcn_mfma_f32_16x16x32_bf16(a, bf1, pj1, 0,0,0);
    }
  }
  #pragma unroll
  for (int r=0;r<4;r++){
    int nl = wave*16 + quad*4 + r;
    float xv = __shfl(xnf, (quad*4 + r)*4, 64);   // producer lane is in this wave
    float v0 = sv0 * __fadd_rn(__fsub_rn(xv, __fmul_rn(2.f,pj0[r])), c2v0);
    float v1 = sv1 * __fadd_rn(__fsub_rn(xv, __fmul_rn(2.f,pj1[r])), c2v1);
    float mx = fmaxf(v0,v1);
    #pragma unroll
    for (int d=1; d<16; d<<=1) mx = fmaxf(mx, __shfl_xor(mx, d, 64));
    float e0 = __expf(v0-mx), e1 = __expf(v1-mx);
    float es = e0+e1;
    #pragma unroll
    for (int d=1; d<16; d<<=1) es += __shfl_xor(es, d, 64);
    float inv = 1.f/es;
    A_lds[nl*32 + ln]      = e0*inv;
    A_lds[nl*32 + 16 + ln] = e1*inv;
  }
  __syncthreads();
  float accE[32];
  #pragma unroll
  for (int p=0;p<32;p++) accE[p]=0.f;
  float asum = 0.f;
  int cbase = wave*8 + h*4;
  #pragma unroll 2
  for (int n=0; n<64; n++){
    float a = A_lds[n*32 + ka];        // 32 dwords, 2-way broadcast, conflict-free
    asum += a;
    const u16* xr = Xs + n*256;
    int sw = (n&15)<<3;
    #pragma unroll
    for (int p8=0; p8<4; p8++){
      u32x4 xv = *(const u32x4*)(xr + ((((cbase + p8)<<3) ^ sw)));
      #pragma unroll
      for (int q=0; q<4; q++){
        u32 w = xv[q];
        float lo = __uint_as_float(w<<16);
        float hi = __uint_as_float(w & 0xffff0000u);
        accE[p8*8 + q*2]   = fmaf(a, lo, accE[p8*8 + q*2]);
        accE[p8*8 + q*2+1] = fmaf(a, hi, accE[p8*8 + q*2+1]);
      }
    }
  }
  int slab = b*128 + g;
  float* Ed = Epart + (size_t)slab*8192 + (size_t)ka*256 + dbase;
  #pragma unroll
  for (int p=0;p<32;p++) Ed[p] = accE[p];
  if (wave==0 && h==0) Asum[slab*32 + ka] = asum;
}

// ---------------- K5b: reduce slabs, subtract asum*cw, relu ----------------
__global__ __launch_bounds__(256) void k5b_reduce(
    const float* __restrict__ Epart, const float* __restrict__ Asum,
    const u16* __restrict__ cw, float* __restrict__ Erelu){
  int id = blockIdx.x*256 + threadIdx.x;
  int d = id & 255, k = (id>>8)&31, b = id>>13;
  float s = 0.f, as = 0.f;
  for (int sl=0; sl<128; sl++){
    s  += Epart[((size_t)(b*128+sl))*8192 + (size_t)k*256 + d];
    as += Asum[(b*128+sl)*32 + k];
  }
  float cv = bf2f(cw[k*256+d]);
  Erelu[(size_t)b*8192 + k*256 + d] = fmaxf(s - as*cv, 0.f);
}

// ---------------- K6a: per-batch L2 norm ----------------
__global__ __launch_bounds__(256) void k6a_norm(
    const float* __restrict__ Erelu, float* __restrict__ consts){
  __shared__ float red[256];
  int b = blockIdx.x, t = threadIdx.x;
  float s = 0.f;
  for (int i=0;i<32;i++){ float e = Erelu[(size_t)b*8192 + i*256 + t]; s = fmaf(e,e,s); }
  red[t] = s; __syncthreads();
  for (int w=128; w>0; w>>=1){ if (t<w) red[t] += red[t+w]; __syncthreads(); }
  if (t==0) consts[RNOFF + b] = 1.f/fmaxf(__fsqrt_rn(red[0]), 1e-12f);
}

// ---------------- K6b: linear partial dots ----------------
__global__ __launch_bounds__(256) void k6b_partial(
    const float* __restrict__ Erelu, const void* lw, const int* __restrict__ flagp,
    float* __restrict__ partials){
  __shared__ float Er[256];
  int kc = blockIdx.x, b = blockIdx.y, t = threadIdx.x;
  int f = flagp[0];
  Er[t] = Erelu[(size_t)b*8192 + kc*256 + t];
  __syncthreads();
  float s = 0.f;
  if (f){
    const float* lwp = (const float*)lw + (size_t)t*8192 + kc*256;
    for (int p=0; p<256; p+=4){
      f32x4 v = *(const f32x4*)(lwp + p);
      #pragma unroll
      for (int q=0;q<4;q++) s = fmaf(Er[p+q], v[q], s);
    }
  } else {
    const u16* lwp = (const u16*)lw + (size_t)t*8192 + kc*256;
    for (int p=0; p<256; p+=8){
      u32x4 v = *(const u32x4*)(lwp + p);
      #pragma unroll
      for (int q=0;q<4;q++){
        u32 w = v[q];
        s = fmaf(Er[p+q*2],   __uint_as_float(w<<16), s);
        s = fmaf(Er[p+q*2+1], __uint_as_float(w & 0xffff0000u), s);
      }
    }
  }
  partials[((size_t)b*32 + kc)*256 + t] = s;
}

// ---------------- K6c: ctx = sigmoid(rnorm*dot + bias) ----------------
__global__ __launch_bounds__(256) void k6c_ctx(
    const float* __restrict__ partials, const float* __restrict__ consts,
    const void* lb, const int* __restrict__ flagp, float* __restrict__ ctx){
  int b = blockIdx.x, t = threadIdx.x;
  int f = flagp[0];
  float s = 0.f;
  for (int kc=0; kc<32; kc++) s += partials[((size_t)b*32+kc)*256 + t];
  float x = fmaf(consts[RNOFF+b], s, ldf(lb,t,f));
  ctx[b*256 + t] = 1.f/(1.f + __expf(-x));
}

// ---------------- K7: out[b][o][n] = ht[b][n][o] * ctx[b][o] ----------------
__global__ __launch_bounds__(256) void k7_out(
    const u16* __restrict__ ht, const float* __restrict__ ctx,
    const int* __restrict__ flagp, void* out){
  __shared__ u16 Ls[64*72];
  int bx = blockIdx.x, oy = blockIdx.y, b = blockIdx.z, t = threadIdx.x;
  int f = flagp[0];
  {
    int nl = t>>2, oc = t&3;
    const u16* src = ht + ((size_t)b*N_ + bx*64 + nl)*256 + oy*64 + oc*16;
    *(u32x4*)(Ls + nl*72 + oc*16)     = *(const u32x4*)src;
    *(u32x4*)(Ls + nl*72 + oc*16 + 8) = *(const u32x4*)(src + 8);
  }
  __syncthreads();
  int ol = t>>2, nc = t&3;
  float cv = ctx[b*256 + oy*64 + ol];
  size_t dstoff = ((size_t)b*DD + oy*64 + ol)*N_ + bx*64 + nc*16;
  if (f){
    float* dst = (float*)out + dstoff;
    #pragma unroll
    for (int wq=0; wq<4; wq++){
      f32x4 v;
      #pragma unroll
      for (int q=0;q<4;q++) v[q] = bf2f(Ls[(nc*16 + wq*4 + q)*72 + ol]) * cv;
      *(f32x4*)(dst + wq*4) = v;
    }
  } else {
    u32 words[8];
    #pragma unroll
    for (int wq=0; wq<8; wq++){
      float v0 = bf2f(Ls[(nc*16 + wq*2)*72 + ol]) * cv;
      float v1 = bf2f(Ls[(nc*16 + wq*2+1)*72 + ol]) * cv;
      words[wq] = (u32)f2bf(v0) | ((u32)f2bf(v1)<<16);
    }
    u16* dst = (u16*)out + dstoff;
    u32x4 w0 = {words[0],words[1],words[2],words[3]};
    u32x4 w1 = {words[4],words[5],words[6],words[7]};
    *(u32x4*)dst     = w0;
    *(u32x4*)(dst+8) = w1;
  }
}

extern "C" void kernel_launch(void* const* d_in, const int* in_sizes, int n_in,
                              void* d_out, int out_size, void* d_ws, size_t ws_size,
                              hipStream_t stream){
  const void* unknown = d_in[0];
  const void* known   = d_in[1];
  const void* uf      = d_in[2];
  const void* kf      = d_in[3];
  const void* w1      = d_in[4];
  const void* cb1     = d_in[5];
  const void* g1      = d_in[6];
  const void* be1     = d_in[7];
  const void* m1      = d_in[8];
  const void* v1      = d_in[9];
  const void* w2      = d_in[10];
  const void* cb2     = d_in[11];
  const void* g2      = d_in[12];
  const void* be2     = d_in[13];
  const void* m2      = d_in[14];
  const void* v2      = d_in[15];
  const void* cw      = d_in[16];
  const void* es      = d_in[17];
  const void* lw      = d_in[18];
  const void* lb      = d_in[19];

  char* ws = (char*)d_ws;
  int*   idx3  = (int*)(ws + OFF_IDX3);
  float* w3    = (float*)(ws + OFF_W3);
  u16*   Ft    = (u16*)(ws + OFF_FT);
  u16*   ht    = Ft;                       // alias: Ft dead after GEMM1 consumes it
  u16*   h1t   = (u16*)(ws + OFF_H1T);
  float* Epart = (float*)(ws + OFF_H1T);   // alias: h1t dead after GEMM2
  float* Asum  = (float*)(ws + OFF_IDX3);  // alias: idx3 dead after k2_interp
  float* Erelu    = (float*)(ws + OFF_ERELU);
  float* partials = (float*)(ws + OFF_PART);
  float* consts   = (float*)(ws + OFF_CONSTS);
  float* ctx      = (float*)(ws + OFF_CTX);
  u16*   W1d   = (u16*)(ws + OFF_W1D);
  u16*   W2d   = (u16*)(ws + OFF_W2D);
  u16*   CWd   = (u16*)(ws + OFF_CWD);
  int*   flagp = (int*)(ws + OFF_FLAG);
  u32*   cmaxp = (u32*)(ws + OFF_FLAG) + 1;
  u16*   Qf    = (u16*)(ws + OFF_QF);      // alias: Ft region, dead until k2
  u16*   Pf    = (u16*)(ws + OFF_PF);

  k_detect<<<1, 256, 0, stream>>>(v1, flagp);
  k_convert<<<800, 256, 0, stream>>>(w1, w2, cw, flagp, W1d, W2d, CWd);
  k_frag<<<320, 256, 0, stream>>>(unknown, known, flagp, Qf, Pf, cmaxp);
  k0_setup<<<1, 256, 0, stream>>>(cb1,g1,be1,m1,v1, cb2,g2,be2,m2,v2, CWd, es, flagp, consts);
  k1_three_nn<<<dim3(128,8), 256, 0, stream>>>(unknown, known, flagp, Qf, Pf, cmaxp, idx3, w3);
  k2_interp<<<dim3(32,4,8), 256, 0, stream>>>(kf, idx3, w3, flagp, Ft);
  k2b_transpose_uf<<<dim3(128,4,8), 256, 0, stream>>>(uf, flagp, Ft);
  gemm_bn_relu<<<dim3(64,2,8), 256, 0, stream>>>(W1d, Ft,  consts, SC1, SH1, h1t, 512);
  gemm_bn_relu<<<dim3(64,2,8), 256, 0, stream>>>(W2d, h1t, consts, SC2, SH2, ht,  256);
  k5_enc_partial<<<dim3(128,8), 256, 0, stream>>>(ht, CWd, consts, Epart, Asum);
  k5b_reduce<<<256, 256, 0, stream>>>(Epart, Asum, CWd, Erelu);
  k6a_norm<<<8, 256, 0, stream>>>(Erelu, consts);
  k6b_partial<<<dim3(32,8), 256, 0, stream>>>(Erelu, lw, flagp, partials);
  k6c_ctx<<<8, 256, 0, stream>>>(partials, consts, lb, flagp, ctx);
  k7_out<<<dim3(128,4,8), 256, 0, stream>>>(ht, ctx, flagp, d_out);
}

// Round 8
// 472.739 us; speedup vs baseline: 2.2999x; 2.2999x over previous
//
#include <hip/hip_runtime.h>
#include <stdint.h>

typedef unsigned short u16;
typedef unsigned int u32;
typedef __attribute__((ext_vector_type(8))) short short8;
typedef __attribute__((ext_vector_type(4))) float f32x4;
typedef __attribute__((ext_vector_type(4))) u32 u32x4;

#define B_ 8
#define N_ 8192
#define M_ 2048
#define DD 256
#define KENC 32

// consts layout (float offsets)
#define SC1 0
#define SH1 256
#define SC2 512
#define SH2 768
#define C2OFF 1024
#define SOFF 1056
#define RNOFF 1088

// ws offsets (bytes)
#define OFF_IDX3   0ull
#define OFF_W3     786432ull
#define OFF_FT     1572864ull
#define OFF_H1T    68681728ull     // Epart aliases this region after GEMM2 (1024 slabs x 8192 f32)
#define OFF_ERELU  102236160ull
#define OFF_PART   102498304ull
#define OFF_CONSTS 102760448ull
#define OFF_CTX    102768640ull
#define OFF_W1D    102776832ull
#define OFF_W2D    103038976ull
#define OFF_CWD    103170048ull
#define OFF_FLAG   103186432ull
// k1 MFMA fragments live in the (pre-k2) dead Ft region
#define OFF_QF     OFF_FT
#define OFF_PF     (OFF_FT + 4194304ull)

// LCAP=32 is round-5-validated (no overflow on this dataset at delta=C^2/2048);
// round 7's LCAP=16 caused fallback storms (750us, 95% idle). With delta halved
// the shell count drops ~2x further -> overflow impossible, 32 is safe.
#define LCAP 32

__device__ __forceinline__ float bf2f(u16 v){ return __uint_as_float(((u32)v)<<16); }
__device__ __forceinline__ u16 f2bf(float f){
  u32 x = __float_as_uint(f);
  return (u16)((x + 0x7FFFu + ((x>>16)&1u)) >> 16);
}
__device__ __forceinline__ float ldf(const void* p, size_t i, int f){
  return f ? ((const float*)p)[i] : bf2f(((const u16*)p)[i]);
}
// async 16B global->LDS (wave-uniform lds base + lane*16)
__device__ __forceinline__ void gl_lds16(const u16* g, u16* l){
  __builtin_amdgcn_global_load_lds(
      (const __attribute__((address_space(1))) void*)g,
      (__attribute__((address_space(3))) void*)l, 16, 0, 0);
}

// ---------------- D: runtime dtype detection from bn_v1 (uniform(0.5,1.5)) ----------------
__global__ __launch_bounds__(256) void k_detect(const void* v1, int* flagp){
  __shared__ int cntb, cntf;
  int t = threadIdx.x;
  if (t==0){ cntb=0; cntf=0; ((u32*)flagp)[1] = 0u; }  // [1] = coord-max accumulator
  __syncthreads();
  float vb = bf2f(((const u16*)v1)[t]);
  if (!(vb > 0.4f && vb < 1.6f)) atomicAdd(&cntb, 1);
  if (t < 64){
    float vf = ((const float*)v1)[t];
    if (!(vf > 0.4f && vf < 1.6f)) atomicAdd(&cntf, 1);
  }
  __syncthreads();
  if (t==0) flagp[0] = (cntb > 0 && cntf == 0) ? 1 : 0;
}

// ---------------- C: convert w1/w2/cw to bf16 ws copies ----------------
__global__ __launch_bounds__(256) void k_convert(
    const void* w1, const void* w2, const void* cwsrc, const int* __restrict__ flagp,
    u16* __restrict__ W1d, u16* __restrict__ W2d, u16* __restrict__ CWd){
  int id = blockIdx.x*256 + threadIdx.x;
  int f = flagp[0];
  if (id < 131072){
    W1d[id] = f ? f2bf(((const float*)w1)[id]) : ((const u16*)w1)[id];
  } else if (id < 196608){
    int j = id - 131072;
    W2d[j] = f ? f2bf(((const float*)w2)[j]) : ((const u16*)w2)[j];
  } else if (id < 204800){
    int j = id - 196608;
    CWd[j] = f ? f2bf(((const float*)cwsrc)[j]) : ((const u16*)cwsrc)[j];
  }
}

// ---------------- K_FRAG: build MFMA distance fragments ----------------
// K-slot layout (32): s = dim*9 + a*3 + bb (a,bb in {h,m,l}): A = -2*u_a[dim], B = k_bb[dim]
// (3-way bf16 split is EXACT: fp32 24-bit mantissa = 8+8+8). slots 27,28: A=x2h,x2l B=1;
// slots 29,30: A=1 B=y2h,y2l; slot 31 = 0. MFMA acc = d_hat = x2+y2-2*dot with
// |d_hat - d_exact| <= C^2*2^-13.3 (fp32 accum + x2/y2 2-split only; coords exact).
__global__ __launch_bounds__(256) void k_frag(
    const void* unknown, const void* known, const int* __restrict__ flagp,
    u16* __restrict__ Qf, u16* __restrict__ Pf, u32* __restrict__ cmaxp){
  __shared__ float mred[256];
  int id = blockIdx.x*256 + threadIdx.x;
  int t = threadIdx.x;
  int f = flagp[0];
  float mx = 0.f;
  u16 S[32];
  if (id < 81920){
    int isq = id < 65536;
    int b, row; size_t o;
    if (isq){ b = id >> 13; row = id & 8191; o = ((size_t)b*N_ + row)*3; }
    else { int j = id - 65536; b = j >> 11; row = j & 2047; o = ((size_t)b*M_ + row)*3; }
    float x = ldf(isq?unknown:known, o, f);
    float y = ldf(isq?unknown:known, o+1, f);
    float z = ldf(isq?unknown:known, o+2, f);
    mx = fmaxf(fmaxf(fabsf(x),fabsf(y)),fabsf(z));
    float s2 = __fadd_rn(__fadd_rn(__fmul_rn(x,x), __fmul_rn(y,y)), __fmul_rn(z,z));
    float c[3] = {x,y,z};
    #pragma unroll
    for (int d3=0; d3<3; d3++){
      float u = c[d3];
      u16 h = f2bf(u);  float r1 = __fsub_rn(u, bf2f(h));     // exact (Sterbenz)
      u16 m2 = f2bf(r1); float r2 = __fsub_rn(r1, bf2f(m2));  // exact
      u16 l2 = f2bf(r2);                                       // exact (<=8 bits left)
      u16 sv[3];
      if (isq){
        sv[0] = f2bf(-2.f*bf2f(h));   // -2*bf16 is exact in bf16
        sv[1] = f2bf(-2.f*bf2f(m2));
        sv[2] = f2bf(-2.f*bf2f(l2));
        #pragma unroll
        for (int a=0; a<3; a++)
          #pragma unroll
          for (int bb=0; bb<3; bb++) S[d3*9 + a*3 + bb] = sv[a];
      } else {
        sv[0] = h; sv[1] = m2; sv[2] = l2;
        #pragma unroll
        for (int a=0; a<3; a++)
          #pragma unroll
          for (int bb=0; bb<3; bb++) S[d3*9 + a*3 + bb] = sv[bb];
      }
    }
    u16 s2h = f2bf(s2); u16 s2l = f2bf(__fsub_rn(s2, bf2f(s2h)));
    if (isq){ S[27]=s2h; S[28]=s2l; S[29]=0x3F80; S[30]=0x3F80; }
    else    { S[27]=0x3F80; S[28]=0x3F80; S[29]=s2h; S[30]=s2l; }
    S[31] = 0;
    u16* dst = isq ? (Qf + ((size_t)(b*512 + (row>>4))*512) + (row&15)*8)
                   : (Pf + ((size_t)(b*128 + (row>>4))*512) + (row&15)*8);
    #pragma unroll
    for (int qd=0; qd<4; qd++){
      u32x4 w;
      #pragma unroll
      for (int q=0; q<4; q++) w[q] = (u32)S[qd*8+q*2] | ((u32)S[qd*8+q*2+1]<<16);
      *(u32x4*)(dst + qd*128) = w;
    }
  }
  mred[t] = mx; __syncthreads();
  for (int w=128; w>0; w>>=1){ if (t<w) mred[t] = fmaxf(mred[t], mred[t+w]); __syncthreads(); }
  if (t==0) atomicMax(cmaxp, __float_as_uint(mred[0]));   // positive floats: uint-monotone
}

// ---------------- K0: fold BN params, codeword norms ----------------
__global__ __launch_bounds__(256) void k0_setup(
    const void* cb1, const void* g1, const void* be1, const void* m1, const void* v1,
    const void* cb2, const void* g2, const void* be2, const void* m2, const void* v2,
    const u16* __restrict__ CWd, const void* es, const int* __restrict__ flagp,
    float* __restrict__ consts){
  int t = threadIdx.x;
  int f = flagp[0];
  {
    float g = ldf(g1,t,f), be = ldf(be1,t,f), m = ldf(m1,t,f), v = ldf(v1,t,f), cb = ldf(cb1,t,f);
    float r = 1.f/sqrtf(v + 1e-5f);
    float sc = g*r;
    consts[SC1+t] = sc; consts[SH1+t] = (cb-m)*sc + be;
  }
  {
    float g = ldf(g2,t,f), be = ldf(be2,t,f), m = ldf(m2,t,f), v = ldf(v2,t,f), cb = ldf(cb2,t,f);
    float r = 1.f/sqrtf(v + 1e-5f);
    float sc = g*r;
    consts[SC2+t] = sc; consts[SH2+t] = (cb-m)*sc + be;
  }
  if (t < KENC){
    float s = 0.f;
    for (int d=0; d<DD; d++){ float c = bf2f(CWd[t*DD+d]); s = fmaf(c,c,s); }
    consts[C2OFF+t] = s;
    consts[SOFF+t]  = ldf(es,t,f);
  }
}

// ---------------- K1: three_nn via MFMA filter + exact recovery (LDS-staged) ----------------
// Pass 1: MFMA d_hat; branchless min+2*med3 on two independent chains; quad butterfly
// -> a2 = 3rd-min d_hat. Pass 2: collect m with d_hat <= a2+2*delta into per-query
// LDS list (delta = C^2/4096 = 2.5x the proven C^2*2^-13.3 error bound -> true top-3
// always included). Final: exact reference distances on the ~3-10 list entries, stable
// (d,idx) lex-insert -> selection identical to scalar incl. ties. Overflow -> full scan.
__global__ __launch_bounds__(256) void k1_three_nn(
    const void* unknown, const void* known, const int* __restrict__ flagp,
    const u16* __restrict__ Qf, const u16* __restrict__ Pf,
    const u32* __restrict__ cmaxp,
    int* __restrict__ idx3, float* __restrict__ w3){
  __shared__ u16 PB[16384];       // 32KB: 32 P-tiles of 512 u16
  __shared__ int lists[64*LCAP];  // 8KB
  __shared__ int lcount[64];
  int b = blockIdx.y, t = threadIdx.x;
  int f = flagp[0];
  if (t < 64) lcount[t] = 0;
  int wave = t>>6, lane = t&63, ln = lane&15, quad = lane>>4;
  int qt = blockIdx.x*4 + wave;
  short8 bq = *(const short8*)(Qf + ((size_t)(b*512 + qt)*512) + lane*8);
  const u16* Pfb = Pf + (size_t)b*65536;
  float C = __uint_as_float(cmaxp[0]);
  float delta = C*C*(1.0f/4096.f);
  // ---- pass 1: 3 smallest d_hat values (two independent chains: even/odd tiles) ----
  float a0=3.4e38f, a1=3.4e38f, a2=3.4e38f;
  float c0=3.4e38f, c1=3.4e38f, c2=3.4e38f;
  for (int ch=0; ch<4; ch++){
    #pragma unroll
    for (int i=0;i<8;i++)
      gl_lds16(Pfb + ch*16384 + i*2048 + wave*512 + lane*8, PB + i*2048 + wave*512);
    __syncthreads();   // drains vmcnt (DMA) before reads
    for (int j=0; j<32; j+=2){
      short8 p0 = *(const short8*)(PB + j*512 + lane*8);
      short8 p1 = *(const short8*)(PB + j*512 + 512 + lane*8);
      f32x4 dA = __builtin_amdgcn_mfma_f32_16x16x32_bf16(p0, bq, (f32x4)0.f, 0,0,0);
      f32x4 dB = __builtin_amdgcn_mfma_f32_16x16x32_bf16(p1, bq, (f32x4)0.f, 0,0,0);
      #pragma unroll
      for (int r=0; r<4; r++){
        float dx = dA[r];
        float t0=fminf(a0,dx), t1=__builtin_amdgcn_fmed3f(a0,a1,dx), t2=__builtin_amdgcn_fmed3f(a1,a2,dx);
        a0=t0; a1=t1; a2=t2;
        float dy = dB[r];
        float s0=fminf(c0,dy), s1=__builtin_amdgcn_fmed3f(c0,c1,dy), s2=__builtin_amdgcn_fmed3f(c1,c2,dy);
        c0=s0; c1=s1; c2=s2;
      }
    }
    __syncthreads();   // chunk fully consumed before restage
  }
  { // merge odd chain into even chain
    float dv3[3] = {c0,c1,c2};
    #pragma unroll
    for (int e=0; e<3; e++){
      float dx = dv3[e];
      float t0=fminf(a0,dx), t1=__builtin_amdgcn_fmed3f(a0,a1,dx), t2=__builtin_amdgcn_fmed3f(a1,a2,dx);
      a0=t0; a1=t1; a2=t2;
    }
  }
  #pragma unroll
  for (int st=16; st<64; st<<=1){   // merge across the 4 quad-lanes of each query
    float o0=__shfl_xor(a0,st,64), o1=__shfl_xor(a1,st,64), o2=__shfl_xor(a2,st,64);
    float dv3[3] = {o0,o1,o2};
    #pragma unroll
    for (int e=0; e<3; e++){
      float dx = dv3[e];
      float t0=fminf(a0,dx), t1=__builtin_amdgcn_fmed3f(a0,a1,dx), t2=__builtin_amdgcn_fmed3f(a1,a2,dx);
      a0=t0; a1=t1; a2=t2;
    }
  }
  float TT = a2 + 2.f*delta;
  // ---- pass 2: collect candidate indices (restaged chunks) ----
  int lq = wave*16 + ln;
  for (int ch=0; ch<4; ch++){
    #pragma unroll
    for (int i=0;i<8;i++)
      gl_lds16(Pfb + ch*16384 + i*2048 + wave*512 + lane*8, PB + i*2048 + wave*512);
    __syncthreads();
    for (int j=0; j<32; j++){
      short8 ap = *(const short8*)(PB + j*512 + lane*8);
      f32x4 dv = __builtin_amdgcn_mfma_f32_16x16x32_bf16(ap, bq, (f32x4)0.f, 0,0,0);
      if (__builtin_expect(dv[0]<=TT || dv[1]<=TT || dv[2]<=TT || dv[3]<=TT, 0)){
        #pragma unroll
        for (int r=0; r<4; r++){
          if (dv[r] <= TT){
            int m = (ch*32+j)*16 + quad*4 + r;
            int ix = atomicAdd(&lcount[lq], 1);
            if (ix < LCAP) lists[lq*LCAP + ix] = m;
          }
        }
      }
    }
    __syncthreads();
  }
  // ---- final: exact distances on the candidate list, stable lex top-3 ----
  if (quad == 0){
    int pid = blockIdx.x*64 + wave*16 + ln;
    size_t uo = ((size_t)b*N_ + pid)*3;
    float ux=ldf(unknown,uo,f), uy=ldf(unknown,uo+1,f), uz=ldf(unknown,uo+2,f);
    float x2 = __fadd_rn(__fadd_rn(__fmul_rn(ux,ux), __fmul_rn(uy,uy)), __fmul_rn(uz,uz));
    // pre-doubled coords: fl(2a*b)=2*fl(a*b), fl(2s+2t)=2*fl(s+t) -> bit-exact vs reference
    float u2x=ux+ux, u2y=uy+uy, u2z=uz+uz;
    float e0=3.4e38f, e1=3.4e38f, e2=3.4e38f;
    int i0=0x7fffffff, i1=0x7fffffff, i2=0x7fffffff;
    int cnt = lcount[lq];
    int lim = (cnt <= LCAP) ? cnt : 0;
    for (int ii=0; ii<lim; ii++){
      int m = lists[lq*LCAP + ii];
      size_t o = ((size_t)b*M_ + m)*3;
      float kx=ldf(known,o,f), ky=ldf(known,o+1,f), kz=ldf(known,o+2,f);
      float y2 = __fadd_rn(__fadd_rn(__fmul_rn(kx,kx), __fmul_rn(ky,ky)), __fmul_rn(kz,kz));
      float dot2 = __fadd_rn(__fadd_rn(__fmul_rn(u2x,kx), __fmul_rn(u2y,ky)), __fmul_rn(u2z,kz));
      float dd = __fadd_rn(__fsub_rn(x2, dot2), y2);
      bool lt0 = (dd < e0) || (dd == e0 && m < i0);
      bool lt1 = (dd < e1) || (dd == e1 && m < i1);
      bool lt2 = (dd < e2) || (dd == e2 && m < i2);
      if (lt0){ e2=e1;i2=i1; e1=e0;i1=i0; e0=dd;i0=m; }
      else if (lt1){ e2=e1;i2=i1; e1=dd;i1=m; }
      else if (lt2){ e2=dd; i2=m; }
    }
    if (cnt > LCAP){  // overflow fallback: exact full scan (never on sane data)
      for (int m=0; m<M_; m++){
        size_t o = ((size_t)b*M_ + m)*3;
        float kx=ldf(known,o,f), ky=ldf(known,o+1,f), kz=ldf(known,o+2,f);
        float y2 = __fadd_rn(__fadd_rn(__fmul_rn(kx,kx), __fmul_rn(ky,ky)), __fmul_rn(kz,kz));
        float dot2 = __fadd_rn(__fadd_rn(__fmul_rn(u2x,kx), __fmul_rn(u2y,ky)), __fmul_rn(u2z,kz));
        float dd = __fadd_rn(__fsub_rn(x2, dot2), y2);
        bool lt0 = (dd < e0) || (dd == e0 && m < i0);
        bool lt1 = (dd < e1) || (dd == e1 && m < i1);
        bool lt2 = (dd < e2) || (dd == e2 && m < i2);
        if (lt0){ e2=e1;i2=i1; e1=e0;i1=i0; e0=dd;i0=m; }
        else if (lt1){ e2=e1;i2=i1; e1=dd;i1=m; }
        else if (lt2){ e2=dd; i2=m; }
      }
    }
    float da = __fsqrt_rn(fmaxf(e0,1e-12f));
    float db = __fsqrt_rn(fmaxf(e1,1e-12f));
    float dc = __fsqrt_rn(fmaxf(e2,1e-12f));
    float r0 = __fdiv_rn(1.f, __fadd_rn(da,1e-8f));
    float r1 = __fdiv_rn(1.f, __fadd_rn(db,1e-8f));
    float r2 = __fdiv_rn(1.f, __fadd_rn(dc,1e-8f));
    float rs = __fadd_rn(__fadd_rn(r0,r1),r2);
    size_t o = ((size_t)b*N_ + pid)*3;
    idx3[o]=i0; idx3[o+1]=i1; idx3[o+2]=i2;
    w3[o]=__fdiv_rn(r0,rs); w3[o+1]=__fdiv_rn(r1,rs); w3[o+2]=__fdiv_rn(r2,rs);
  }
}

// ---------------- K2: three_interpolate -> Ft[:, :, 0:256] (point-major) ----------------
__global__ __launch_bounds__(256) void k2_interp(
    const void* kf, const int* __restrict__ idx3,
    const float* __restrict__ w3, const int* __restrict__ flagp, u16* __restrict__ Ft){
  __shared__ u16 Ls[M_*8]; // [i][c], 32KB
  int ct = blockIdx.x;  // 0..31 (channel tile of 8)
  int rg = blockIdx.y;  // 0..3 (rep group)
  int b = blockIdx.z, t = threadIdx.x;
  int f = flagp[0];
  for (int cp=0; cp<4; cp++){
    int c0 = ct*8 + cp*2;
    size_t base0 = ((size_t)b*DD + c0)*M_;
    size_t base1 = base0 + M_;
    for (int i=t; i<M_; i+=256){
      float f0 = ldf(kf, base0+i, f);
      float f1 = ldf(kf, base1+i, f);
      u32 w = (u32)f2bf(f0) | ((u32)f2bf(f1)<<16);
      *(u32*)(Ls + i*8 + cp*2) = w;
    }
  }
  __syncthreads();
  for (int rep=rg*8; rep<rg*8+8; rep++){
    int pid = rep*256 + t;
    size_t o3 = ((size_t)b*N_ + pid)*3;
    int ia = idx3[o3], ib = idx3[o3+1], ic = idx3[o3+2];
    float wa = w3[o3], wb = w3[o3+1], wc = w3[o3+2];
    short8 va = *(const short8*)(Ls + ia*8);
    short8 vb = *(const short8*)(Ls + ib*8);
    short8 vc = *(const short8*)(Ls + ic*8);
    u32x4 pk;
    #pragma unroll
    for (int cq=0; cq<4; cq++){
      float fa0 = bf2f((u16)va[cq*2]),   fb0 = bf2f((u16)vb[cq*2]),   fc0 = bf2f((u16)vc[cq*2]);
      float fa1 = bf2f((u16)va[cq*2+1]), fb1 = bf2f((u16)vb[cq*2+1]), fc1 = bf2f((u16)vc[cq*2+1]);
      float v0 = fmaf(wc, fc0, fmaf(wb, fb0, wa*fa0));
      float v1 = fmaf(wc, fc1, fmaf(wb, fb1, wa*fa1));
      pk[cq] = (u32)f2bf(v0) | ((u32)f2bf(v1)<<16);
    }
    *(u32x4*)(Ft + ((size_t)b*N_ + pid)*512 + ct*8) = pk;
  }
}

// ---------------- K2b: transpose unknow_feats -> Ft[:, :, 256:512] ----------------
__global__ __launch_bounds__(256) void k2b_transpose_uf(
    const void* uf, const int* __restrict__ flagp, u16* __restrict__ Ft){
  __shared__ u16 Ls[64*72];
  int bx = blockIdx.x, cy = blockIdx.y, b = blockIdx.z, t = threadIdx.x;
  int f = flagp[0];
  {
    int n = t & 63, cg = t >> 6;
    for (int i=0; i<16; i++){
      int c = cg*16 + i;
      Ls[n*72 + c] = f2bf(ldf(uf, ((size_t)b*DD + cy*64 + c)*N_ + bx*64 + n, f));
    }
  }
  __syncthreads();
  int nl = t>>2, cc = t&3;
  u16* dst = Ft + ((size_t)b*N_ + bx*64 + nl)*512 + 256 + cy*64 + cc*16;
  *(u32x4*)dst     = *(const u32x4*)(Ls + nl*72 + cc*16);
  *(u32x4*)(dst+8) = *(const u32x4*)(Ls + nl*72 + cc*16 + 8);
}

// ---------------- K3/K4: MFMA GEMM, BK=64, global_load_lds + XOR-swizzled LDS ----------------
__global__ __launch_bounds__(256) void gemm_bn_relu(
    const u16* __restrict__ W, const u16* __restrict__ Fin,
    const float* __restrict__ consts, int sc_off, int sh_off,
    u16* __restrict__ Out, int K){
  __shared__ u16 SM[17408]; // As(8192)+Bs(8192) u16 in K-loop; Cs(128x136) in epilogue
  u16* As = SM; u16* Bs = SM + 8192;
  int b = blockIdx.z, ot = blockIdx.y*128, nt = blockIdx.x*128;
  int t = threadIdx.x, wave = t>>6, lane = t&63, ln = lane&15, quad = lane>>4;
  int wo = (wave&1)*64, wn = (wave>>1)*64;
  f32x4 acc[4][4];
  #pragma unroll
  for (int i=0;i<4;i++)
    #pragma unroll
    for (int j=0;j<4;j++) acc[i][j] = (f32x4)0.f;
  const u16* Wp = W + (size_t)ot*K;
  const u16* Fp = Fin + ((size_t)b*N_ + nt)*K;
  for (int kk=0; kk<K; kk+=64){
    #pragma unroll
    for (int i=0;i<4;i++){
      int c = wave*256 + i*64 + lane;          // chunk slot 0..1023
      int r = c>>3, k8 = (c&7) ^ (r&7);
      const u16* gA = Wp + (size_t)r*K + kk + k8*8;
      const u16* gB = Fp + (size_t)r*K + kk + k8*8;
      gl_lds16(gA, As + (size_t)(wave*256 + i*64)*8);
      gl_lds16(gB, Bs + (size_t)(wave*256 + i*64)*8);
    }
    __syncthreads();
    #pragma unroll
    for (int kh=0; kh<2; kh++){
      short8 af[4], bfr[4];
      #pragma unroll
      for (int i=0;i<4;i++){
        int R = wo + i*16 + ln, C = kh*4 + quad;
        af[i] = *(const short8*)(As + (size_t)(R*8 + (C^(R&7)))*8);
      }
      #pragma unroll
      for (int j=0;j<4;j++){
        int R = wn + j*16 + ln, C = kh*4 + quad;
        bfr[j] = *(const short8*)(Bs + (size_t)(R*8 + (C^(R&7)))*8);
      }
      #pragma unroll
      for (int i=0;i<4;i++)
        #pragma unroll
        for (int j=0;j<4;j++)
          acc[i][j] = __builtin_amdgcn_mfma_f32_16x16x32_bf16(af[i], bfr[j], acc[i][j], 0,0,0);
    }
    __syncthreads();
  }
  u16* Cs = SM; // stride 136
  #pragma unroll
  for (int i=0;i<4;i++){
    #pragma unroll
    for (int r=0;r<4;r++){
      int ol = wo + i*16 + quad*4 + r;
      float sc = consts[sc_off + ot + ol], sh = consts[sh_off + ot + ol];
      #pragma unroll
      for (int j=0;j<4;j++){
        float v = fmaxf(fmaf(acc[i][j][r], sc, sh), 0.f);
        Cs[(wn + j*16 + ln)*136 + ol] = f2bf(v);
      }
    }
  }
  __syncthreads();
  int nl = t>>1, half = t&1;
  u16* dst = Out + ((size_t)b*N_ + nt + nl)*256 + ot + half*64;
  const u16* srcr = Cs + nl*136 + half*64;
  #pragma unroll
  for (int c=0;c<8;c++)
    *(u32x4*)(dst + c*8) = *(const u32x4*)(srcr + c*8);
}

// ---------------- K5: encoding partials ----------------
__global__ __launch_bounds__(256, 6) void k5_enc_partial(
    const u16* __restrict__ X, const u16* __restrict__ cw,
    const float* __restrict__ consts, float* __restrict__ Epart,
    float* __restrict__ Asum){
  __shared__ u16 Xs[64*256];      // 32KB, swizzled
  __shared__ float A_lds[64*32];  // 8KB
  int g = blockIdx.x, b = blockIdx.y, t = threadIdx.x;
  int wave = t>>6, lane = t&63, ln = lane&15, quad = lane>>4;
  int ka = lane>>1, h = lane&1;          // accumulation roles: k index, d-half
  int dbase = wave*64 + h*32;            // 32 consecutive d per thread
  float c2v0 = consts[C2OFF + ln], c2v1 = consts[C2OFF + 16 + ln];
  float sv0  = consts[SOFF + ln],  sv1  = consts[SOFF + 16 + ln];
  int n0 = g*64;
  const u16* Xp = X + ((size_t)b*N_ + n0)*256;
  #pragma unroll
  for (int i=0;i<8;i++){
    int ch = t + i*256;
    int r = ch>>5, cc = ch&31;
    *(u32x4*)(Xs + r*256 + ((cc ^ (r&15))<<3)) = *(const u32x4*)(Xp + r*256 + cc*8);
  }
  __syncthreads();
  float xnf;
  {
    int row = t>>2, part = t&3;
    float s = 0.f;
    #pragma unroll
    for (int j=0;j<8;j++){
      int cc = part*8 + j;
      short8 xv = *(const short8*)(Xs + row*256 + ((cc ^ (row&15))<<3));
      #pragma unroll
      for (int q=0;q<8;q++){ float x = bf2f((u16)xv[q]); s = fmaf(x,x,s); }
    }
    s += __shfl_xor(s,1,64);
    s += __shfl_xor(s,2,64);
    xnf = s;
  }
  f32x4 pj0 = (f32x4)0.f, pj1 = (f32x4)0.f;
  {
    int row = wave*16 + ln;
    #pragma unroll
    for (int kk=0; kk<256; kk+=32){
      int cc = (kk>>3) + quad;
      short8 a   = *(const short8*)(Xs + row*256 + ((cc ^ (row&15))<<3));
      short8 bf0 = *(const short8*)(cw + (size_t)ln*256 + kk + quad*8);
      short8 bf1 = *(const short8*)(cw + (size_t)(16+ln)*256 + kk + quad*8);
      pj0 = __builtin_amdgcn_mfma_f32_16x16x32_bf16(a, bf0, pj0, 0,0,0);
      pj1 = __builtin_amdgcn_mfma_f32_16x16x32_bf16(a, bf1, pj1, 0,0,0);
    }
  }
  #pragma unroll
  for (int r=0;r<4;r++){
    int nl = wave*16 + quad*4 + r;
    float xv = __shfl(xnf, (quad*4 + r)*4, 64);   // producer lane is in this wave
    float v0 = sv0 * __fadd_rn(__fsub_rn(xv, __fmul_rn(2.f,pj0[r])), c2v0);
    float v1 = sv1 * __fadd_rn(__fsub_rn(xv, __fmul_rn(2.f,pj1[r])), c2v1);
    float mx = fmaxf(v0,v1);
    #pragma unroll
    for (int d=1; d<16; d<<=1) mx = fmaxf(mx, __shfl_xor(mx, d, 64));
    float e0 = __expf(v0-mx), e1 = __expf(v1-mx);
    float es = e0+e1;
    #pragma unroll
    for (int d=1; d<16; d<<=1) es += __shfl_xor(es, d, 64);
    float inv = 1.f/es;
    A_lds[nl*32 + ln]      = e0*inv;
    A_lds[nl*32 + 16 + ln] = e1*inv;
  }
  __syncthreads();
  float accE[32];
  #pragma unroll
  for (int p=0;p<32;p++) accE[p]=0.f;
  float asum = 0.f;
  int cbase = wave*8 + h*4;
  #pragma unroll 2
  for (int n=0; n<64; n++){
    float a = A_lds[n*32 + ka];        // 32 dwords, 2-way broadcast, conflict-free
    asum += a;
    const u16* xr = Xs + n*256;
    int sw = (n&15)<<3;
    #pragma unroll
    for (int p8=0; p8<4; p8++){
      u32x4 xv = *(const u32x4*)(xr + ((((cbase + p8)<<3) ^ sw)));
      #pragma unroll
      for (int q=0; q<4; q++){
        u32 w = xv[q];
        float lo = __uint_as_float(w<<16);
        float hi = __uint_as_float(w & 0xffff0000u);
        accE[p8*8 + q*2]   = fmaf(a, lo, accE[p8*8 + q*2]);
        accE[p8*8 + q*2+1] = fmaf(a, hi, accE[p8*8 + q*2+1]);
      }
    }
  }
  int slab = b*128 + g;
  float* Ed = Epart + (size_t)slab*8192 + (size_t)ka*256 + dbase;
  #pragma unroll
  for (int p=0;p<32;p++) Ed[p] = accE[p];
  if (wave==0 && h==0) Asum[slab*32 + ka] = asum;
}

// ---------------- K5b: reduce slabs, subtract asum*cw, relu ----------------
__global__ __launch_bounds__(256) void k5b_reduce(
    const float* __restrict__ Epart, const float* __restrict__ Asum,
    const u16* __restrict__ cw, float* __restrict__ Erelu){
  int id = blockIdx.x*256 + threadIdx.x;
  int d = id & 255, k = (id>>8)&31, b = id>>13;
  float s = 0.f, as = 0.f;
  for (int sl=0; sl<128; sl++){
    s  += Epart[((size_t)(b*128+sl))*8192 + (size_t)k*256 + d];
    as += Asum[(b*128+sl)*32 + k];
  }
  float cv = bf2f(cw[k*256+d]);
  Erelu[(size_t)b*8192 + k*256 + d] = fmaxf(s - as*cv, 0.f);
}

// ---------------- K6a: per-batch L2 norm ----------------
__global__ __launch_bounds__(256) void k6a_norm(
    const float* __restrict__ Erelu, float* __restrict__ consts){
  __shared__ float red[256];
  int b = blockIdx.x, t = threadIdx.x;
  float s = 0.f;
  for (int i=0;i<32;i++){ float e = Erelu[(size_t)b*8192 + i*256 + t]; s = fmaf(e,e,s); }
  red[t] = s; __syncthreads();
  for (int w=128; w>0; w>>=1){ if (t<w) red[t] += red[t+w]; __syncthreads(); }
  if (t==0) consts[RNOFF + b] = 1.f/fmaxf(__fsqrt_rn(red[0]), 1e-12f);
}

// ---------------- K6b: linear partial dots ----------------
__global__ __launch_bounds__(256) void k6b_partial(
    const float* __restrict__ Erelu, const void* lw, const int* __restrict__ flagp,
    float* __restrict__ partials){
  __shared__ float Er[256];
  int kc = blockIdx.x, b = blockIdx.y, t = threadIdx.x;
  int f = flagp[0];
  Er[t] = Erelu[(size_t)b*8192 + kc*256 + t];
  __syncthreads();
  float s = 0.f;
  if (f){
    const float* lwp = (const float*)lw + (size_t)t*8192 + kc*256;
    for (int p=0; p<256; p+=4){
      f32x4 v = *(const f32x4*)(lwp + p);
      #pragma unroll
      for (int q=0;q<4;q++) s = fmaf(Er[p+q], v[q], s);
    }
  } else {
    const u16* lwp = (const u16*)lw + (size_t)t*8192 + kc*256;
    for (int p=0; p<256; p+=8){
      u32x4 v = *(const u32x4*)(lwp + p);
      #pragma unroll
      for (int q=0;q<4;q++){
        u32 w = v[q];
        s = fmaf(Er[p+q*2],   __uint_as_float(w<<16), s);
        s = fmaf(Er[p+q*2+1], __uint_as_float(w & 0xffff0000u), s);
      }
    }
  }
  partials[((size_t)b*32 + kc)*256 + t] = s;
}

// ---------------- K6c: ctx = sigmoid(rnorm*dot + bias) ----------------
__global__ __launch_bounds__(256) void k6c_ctx(
    const float* __restrict__ partials, const float* __restrict__ consts,
    const void* lb, const int* __restrict__ flagp, float* __restrict__ ctx){
  int b = blockIdx.x, t = threadIdx.x;
  int f = flagp[0];
  float s = 0.f;
  for (int kc=0; kc<32; kc++) s += partials[((size_t)b*32+kc)*256 + t];
  float x = fmaf(consts[RNOFF+b], s, ldf(lb,t,f));
  ctx[b*256 + t] = 1.f/(1.f + __expf(-x));
}

// ---------------- K7: out[b][o][n] = ht[b][n][o] * ctx[b][o] ----------------
__global__ __launch_bounds__(256) void k7_out(
    const u16* __restrict__ ht, const float* __restrict__ ctx,
    const int* __restrict__ flagp, void* out){
  __shared__ u16 Ls[64*72];
  int bx = blockIdx.x, oy = blockIdx.y, b = blockIdx.z, t = threadIdx.x;
  int f = flagp[0];
  {
    int nl = t>>2, oc = t&3;
    const u16* src = ht + ((size_t)b*N_ + bx*64 + nl)*256 + oy*64 + oc*16;
    *(u32x4*)(Ls + nl*72 + oc*16)     = *(const u32x4*)src;
    *(u32x4*)(Ls + nl*72 + oc*16 + 8) = *(const u32x4*)(src + 8);
  }
  __syncthreads();
  int ol = t>>2, nc = t&3;
  float cv = ctx[b*256 + oy*64 + ol];
  size_t dstoff = ((size_t)b*DD + oy*64 + ol)*N_ + bx*64 + nc*16;
  if (f){
    float* dst = (float*)out + dstoff;
    #pragma unroll
    for (int wq=0; wq<4; wq++){
      f32x4 v;
      #pragma unroll
      for (int q=0;q<4;q++) v[q] = bf2f(Ls[(nc*16 + wq*4 + q)*72 + ol]) * cv;
      *(f32x4*)(dst + wq*4) = v;
    }
  } else {
    u32 words[8];
    #pragma unroll
    for (int wq=0; wq<8; wq++){
      float v0 = bf2f(Ls[(nc*16 + wq*2)*72 + ol]) * cv;
      float v1 = bf2f(Ls[(nc*16 + wq*2+1)*72 + ol]) * cv;
      words[wq] = (u32)f2bf(v0) | ((u32)f2bf(v1)<<16);
    }
    u16* dst = (u16*)out + dstoff;
    u32x4 w0 = {words[0],words[1],words[2],words[3]};
    u32x4 w1 = {words[4],words[5],words[6],words[7]};
    *(u32x4*)dst     = w0;
    *(u32x4*)(dst+8) = w1;
  }
}

extern "C" void kernel_launch(void* const* d_in, const int* in_sizes, int n_in,
                              void* d_out, int out_size, void* d_ws, size_t ws_size,
                              hipStream_t stream){
  const void* unknown = d_in[0];
  const void* known   = d_in[1];
  const void* uf      = d_in[2];
  const void* kf      = d_in[3];
  const void* w1      = d_in[4];
  const void* cb1     = d_in[5];
  const void* g1      = d_in[6];
  const void* be1     = d_in[7];
  const void* m1      = d_in[8];
  const void* v1      = d_in[9];
  const void* w2      = d_in[10];
  const void* cb2     = d_in[11];
  const void* g2      = d_in[12];
  const void* be2     = d_in[13];
  const void* m2      = d_in[14];
  const void* v2      = d_in[15];
  const void* cw      = d_in[16];
  const void* es      = d_in[17];
  const void* lw      = d_in[18];
  const void* lb      = d_in[19];

  char* ws = (char*)d_ws;
  int*   idx3  = (int*)(ws + OFF_IDX3);
  float* w3    = (float*)(ws + OFF_W3);
  u16*   Ft    = (u16*)(ws + OFF_FT);
  u16*   ht    = Ft;                       // alias: Ft dead after GEMM1 consumes it
  u16*   h1t   = (u16*)(ws + OFF_H1T);
  float* Epart = (float*)(ws + OFF_H1T);   // alias: h1t dead after GEMM2
  float* Asum  = (float*)(ws + OFF_IDX3);  // alias: idx3 dead after k2_interp
  float* Erelu    = (float*)(ws + OFF_ERELU);
  float* partials = (float*)(ws + OFF_PART);
  float* consts   = (float*)(ws + OFF_CONSTS);
  float* ctx      = (float*)(ws + OFF_CTX);
  u16*   W1d   = (u16*)(ws + OFF_W1D);
  u16*   W2d   = (u16*)(ws + OFF_W2D);
  u16*   CWd   = (u16*)(ws + OFF_CWD);
  int*   flagp = (int*)(ws + OFF_FLAG);
  u32*   cmaxp = (u32*)(ws + OFF_FLAG) + 1;
  u16*   Qf    = (u16*)(ws + OFF_QF);      // alias: Ft region, dead until k2
  u16*   Pf    = (u16*)(ws + OFF_PF);

  k_detect<<<1, 256, 0, stream>>>(v1, flagp);
  k_convert<<<800, 256, 0, stream>>>(w1, w2, cw, flagp, W1d, W2d, CWd);
  k_frag<<<320, 256, 0, stream>>>(unknown, known, flagp, Qf, Pf, cmaxp);
  k0_setup<<<1, 256, 0, stream>>>(cb1,g1,be1,m1,v1, cb2,g2,be2,m2,v2, CWd, es, flagp, consts);
  k1_three_nn<<<dim3(128,8), 256, 0, stream>>>(unknown, known, flagp, Qf, Pf, cmaxp, idx3, w3);
  k2_interp<<<dim3(32,4,8), 256, 0, stream>>>(kf, idx3, w3, flagp, Ft);
  k2b_transpose_uf<<<dim3(128,4,8), 256, 0, stream>>>(uf, flagp, Ft);
  gemm_bn_relu<<<dim3(64,2,8), 256, 0, stream>>>(W1d, Ft,  consts, SC1, SH1, h1t, 512);
  gemm_bn_relu<<<dim3(64,2,8), 256, 0, stream>>>(W2d, h1t, consts, SC2, SH2, ht,  256);
  k5_enc_partial<<<dim3(128,8), 256, 0, stream>>>(ht, CWd, consts, Epart, Asum);
  k5b_reduce<<<256, 256, 0, stream>>>(Epart, Asum, CWd, Erelu);
  k6a_norm<<<8, 256, 0, stream>>>(Erelu, consts);
  k6b_partial<<<dim3(32,8), 256, 0, stream>>>(Erelu, lw, flagp, partials);
  k6c_ctx<<<8, 256, 0, stream>>>(partials, consts, lb, flagp, ctx);
  k7_out<<<dim3(128,4,8), 256, 0, stream>>>(ht, ctx, flagp, d_out);
}

// Round 9
// 450.690 us; speedup vs baseline: 2.4125x; 1.0489x over previous
//
#include <hip/hip_runtime.h>
#include <stdint.h>

typedef unsigned short u16;
typedef unsigned int u32;
typedef __attribute__((ext_vector_type(8))) short short8;
typedef __attribute__((ext_vector_type(4))) float f32x4;
typedef __attribute__((ext_vector_type(4))) u32 u32x4;

#define B_ 8
#define N_ 8192
#define M_ 2048
#define DD 256
#define KENC 32

// consts layout (float offsets)
#define SC1 0
#define SH1 256
#define SC2 512
#define SH2 768
#define C2OFF 1024
#define SOFF 1056
#define RNOFF 1088

// ws offsets (bytes)
#define OFF_IDX3   0ull
#define OFF_W3     786432ull
#define OFF_FT     1572864ull
#define OFF_H1T    68681728ull     // Epart aliases this region after GEMM2 (1024 slabs x 8192 f32)
#define OFF_ERELU  102236160ull
#define OFF_PART   102498304ull
#define OFF_CONSTS 102760448ull
#define OFF_CTX    102768640ull
#define OFF_W1D    102776832ull
#define OFF_W2D    103038976ull
#define OFF_CWD    103170048ull
#define OFF_FLAG   103186432ull
// k1 MFMA fragments live in the (pre-k2) dead Ft region
#define OFF_QF     OFF_FT
#define OFF_PF     (OFF_FT + 4194304ull)

// LCAP=24 with delta=C^2/8192: max cnt ~10 on this data (round-7/8 bracketing:
// delta=C^2/2048 gives cnt in (16,32]; extras scale ~linearly with delta).
// 2*delta = C^2*2^-12 >= 2*eps = C^2*2^-12.3 -> filter still provably safe.
#define LCAP 24

__device__ __forceinline__ float bf2f(u16 v){ return __uint_as_float(((u32)v)<<16); }
__device__ __forceinline__ u16 f2bf(float f){
  u32 x = __float_as_uint(f);
  return (u16)((x + 0x7FFFu + ((x>>16)&1u)) >> 16);
}
__device__ __forceinline__ float ldf(const void* p, size_t i, int f){
  return f ? ((const float*)p)[i] : bf2f(((const u16*)p)[i]);
}
// async 16B global->LDS (wave-uniform lds base + lane*16)
__device__ __forceinline__ void gl_lds16(const u16* g, u16* l){
  __builtin_amdgcn_global_load_lds(
      (const __attribute__((address_space(1))) void*)g,
      (__attribute__((address_space(3))) void*)l, 16, 0, 0);
}

// ---------------- D: runtime dtype detection from bn_v1 (uniform(0.5,1.5)) ----------------
__global__ __launch_bounds__(256) void k_detect(const void* v1, int* flagp){
  __shared__ int cntb, cntf;
  int t = threadIdx.x;
  if (t==0){ cntb=0; cntf=0; ((u32*)flagp)[1] = 0u; }  // [1] = coord-max accumulator
  __syncthreads();
  float vb = bf2f(((const u16*)v1)[t]);
  if (!(vb > 0.4f && vb < 1.6f)) atomicAdd(&cntb, 1);
  if (t < 64){
    float vf = ((const float*)v1)[t];
    if (!(vf > 0.4f && vf < 1.6f)) atomicAdd(&cntf, 1);
  }
  __syncthreads();
  if (t==0) flagp[0] = (cntb > 0 && cntf == 0) ? 1 : 0;
}

// ---------------- C: convert w1/w2/cw to bf16 ws copies ----------------
__global__ __launch_bounds__(256) void k_convert(
    const void* w1, const void* w2, const void* cwsrc, const int* __restrict__ flagp,
    u16* __restrict__ W1d, u16* __restrict__ W2d, u16* __restrict__ CWd){
  int id = blockIdx.x*256 + threadIdx.x;
  int f = flagp[0];
  if (id < 131072){
    W1d[id] = f ? f2bf(((const float*)w1)[id]) : ((const u16*)w1)[id];
  } else if (id < 196608){
    int j = id - 131072;
    W2d[j] = f ? f2bf(((const float*)w2)[j]) : ((const u16*)w2)[j];
  } else if (id < 204800){
    int j = id - 196608;
    CWd[j] = f ? f2bf(((const float*)cwsrc)[j]) : ((const u16*)cwsrc)[j];
  }
}

// ---------------- K_FRAG: build MFMA distance fragments ----------------
// K-slot layout (32): s = dim*9 + a*3 + bb (a,bb in {h,m,l}): A = -2*u_a[dim], B = k_bb[dim]
// (3-way bf16 split is EXACT: fp32 24-bit mantissa = 8+8+8). slots 27,28: A=x2h,x2l B=1;
// slots 29,30: A=1 B=y2h,y2l; slot 31 = 0. MFMA acc = d_hat = x2+y2-2*dot with
// |d_hat - d_exact| <= C^2*2^-13.3 (fp32 accum + x2/y2 2-split only; coords exact).
__global__ __launch_bounds__(256) void k_frag(
    const void* unknown, const void* known, const int* __restrict__ flagp,
    u16* __restrict__ Qf, u16* __restrict__ Pf, u32* __restrict__ cmaxp){
  __shared__ float mred[256];
  int id = blockIdx.x*256 + threadIdx.x;
  int t = threadIdx.x;
  int f = flagp[0];
  float mx = 0.f;
  u16 S[32];
  if (id < 81920){
    int isq = id < 65536;
    int b, row; size_t o;
    if (isq){ b = id >> 13; row = id & 8191; o = ((size_t)b*N_ + row)*3; }
    else { int j = id - 65536; b = j >> 11; row = j & 2047; o = ((size_t)b*M_ + row)*3; }
    float x = ldf(isq?unknown:known, o, f);
    float y = ldf(isq?unknown:known, o+1, f);
    float z = ldf(isq?unknown:known, o+2, f);
    mx = fmaxf(fmaxf(fabsf(x),fabsf(y)),fabsf(z));
    float s2 = __fadd_rn(__fadd_rn(__fmul_rn(x,x), __fmul_rn(y,y)), __fmul_rn(z,z));
    float c[3] = {x,y,z};
    #pragma unroll
    for (int d3=0; d3<3; d3++){
      float u = c[d3];
      u16 h = f2bf(u);  float r1 = __fsub_rn(u, bf2f(h));     // exact (Sterbenz)
      u16 m2 = f2bf(r1); float r2 = __fsub_rn(r1, bf2f(m2));  // exact
      u16 l2 = f2bf(r2);                                       // exact (<=8 bits left)
      u16 sv[3];
      if (isq){
        sv[0] = f2bf(-2.f*bf2f(h));   // -2*bf16 is exact in bf16
        sv[1] = f2bf(-2.f*bf2f(m2));
        sv[2] = f2bf(-2.f*bf2f(l2));
        #pragma unroll
        for (int a=0; a<3; a++)
          #pragma unroll
          for (int bb=0; bb<3; bb++) S[d3*9 + a*3 + bb] = sv[a];
      } else {
        sv[0] = h; sv[1] = m2; sv[2] = l2;
        #pragma unroll
        for (int a=0; a<3; a++)
          #pragma unroll
          for (int bb=0; bb<3; bb++) S[d3*9 + a*3 + bb] = sv[bb];
      }
    }
    u16 s2h = f2bf(s2); u16 s2l = f2bf(__fsub_rn(s2, bf2f(s2h)));
    if (isq){ S[27]=s2h; S[28]=s2l; S[29]=0x3F80; S[30]=0x3F80; }
    else    { S[27]=0x3F80; S[28]=0x3F80; S[29]=s2h; S[30]=s2l; }
    S[31] = 0;
    u16* dst = isq ? (Qf + ((size_t)(b*512 + (row>>4))*512) + (row&15)*8)
                   : (Pf + ((size_t)(b*128 + (row>>4))*512) + (row&15)*8);
    #pragma unroll
    for (int qd=0; qd<4; qd++){
      u32x4 w;
      #pragma unroll
      for (int q=0; q<4; q++) w[q] = (u32)S[qd*8+q*2] | ((u32)S[qd*8+q*2+1]<<16);
      *(u32x4*)(dst + qd*128) = w;
    }
  }
  mred[t] = mx; __syncthreads();
  for (int w=128; w>0; w>>=1){ if (t<w) mred[t] = fmaxf(mred[t], mred[t+w]); __syncthreads(); }
  if (t==0) atomicMax(cmaxp, __float_as_uint(mred[0]));   // positive floats: uint-monotone
}

// ---------------- K0: fold BN params, codeword norms ----------------
__global__ __launch_bounds__(256) void k0_setup(
    const void* cb1, const void* g1, const void* be1, const void* m1, const void* v1,
    const void* cb2, const void* g2, const void* be2, const void* m2, const void* v2,
    const u16* __restrict__ CWd, const void* es, const int* __restrict__ flagp,
    float* __restrict__ consts){
  int t = threadIdx.x;
  int f = flagp[0];
  {
    float g = ldf(g1,t,f), be = ldf(be1,t,f), m = ldf(m1,t,f), v = ldf(v1,t,f), cb = ldf(cb1,t,f);
    float r = 1.f/sqrtf(v + 1e-5f);
    float sc = g*r;
    consts[SC1+t] = sc; consts[SH1+t] = (cb-m)*sc + be;
  }
  {
    float g = ldf(g2,t,f), be = ldf(be2,t,f), m = ldf(m2,t,f), v = ldf(v2,t,f), cb = ldf(cb2,t,f);
    float r = 1.f/sqrtf(v + 1e-5f);
    float sc = g*r;
    consts[SC2+t] = sc; consts[SH2+t] = (cb-m)*sc + be;
  }
  if (t < KENC){
    float s = 0.f;
    for (int d=0; d<DD; d++){ float c = bf2f(CWd[t*DD+d]); s = fmaf(c,c,s); }
    consts[C2OFF+t] = s;
    consts[SOFF+t]  = ldf(es,t,f);
  }
}

// ---------------- K1: three_nn via MFMA filter + exact recovery (LDS-staged) ----------------
// Round-8 analysis: LDS 41.5KB -> 3 blocks/CU resident but 4 blocks/CU of grid ->
// two-phase execution with a lone straggler block (occupancy 22.9%). Fixes:
// (1) LCAP 24 -> LDS 39168B -> 4 blocks/CU, single phase (launch_bounds(256,4));
// (2) pass-1 selection on FOUR independent min/med3 chains (was 2) -> halves the
//     serial dep-chain latency. Semantics unchanged (multiset-union of chains).
__global__ __launch_bounds__(256, 4) void k1_three_nn(
    const void* unknown, const void* known, const int* __restrict__ flagp,
    const u16* __restrict__ Qf, const u16* __restrict__ Pf,
    const u32* __restrict__ cmaxp,
    int* __restrict__ idx3, float* __restrict__ w3){
  __shared__ u16 PB[16384];       // 32KB: 32 P-tiles of 512 u16
  __shared__ int lists[64*LCAP];  // 6KB
  __shared__ int lcount[64];
  int b = blockIdx.y, t = threadIdx.x;
  int f = flagp[0];
  if (t < 64) lcount[t] = 0;
  int wave = t>>6, lane = t&63, ln = lane&15, quad = lane>>4;
  int qt = blockIdx.x*4 + wave;
  short8 bq = *(const short8*)(Qf + ((size_t)(b*512 + qt)*512) + lane*8);
  const u16* Pfb = Pf + (size_t)b*65536;
  float C = __uint_as_float(cmaxp[0]);
  float delta = C*C*(1.0f/8192.f);
  // ---- pass 1: 3 smallest d_hat values on 4 independent chains ----
  float a0=3.4e38f, a1=3.4e38f, a2=3.4e38f;
  float c0=3.4e38f, c1=3.4e38f, c2=3.4e38f;
  float e0=3.4e38f, e1=3.4e38f, e2=3.4e38f;
  float g0=3.4e38f, g1=3.4e38f, g2=3.4e38f;
  for (int ch=0; ch<4; ch++){
    #pragma unroll
    for (int i=0;i<8;i++)
      gl_lds16(Pfb + ch*16384 + i*2048 + wave*512 + lane*8, PB + i*2048 + wave*512);
    __syncthreads();   // drains vmcnt (DMA) before reads
    for (int j=0; j<32; j+=4){
      short8 p0 = *(const short8*)(PB + j*512 + lane*8);
      short8 p1 = *(const short8*)(PB + j*512 + 512 + lane*8);
      short8 p2 = *(const short8*)(PB + j*512 + 1024 + lane*8);
      short8 p3 = *(const short8*)(PB + j*512 + 1536 + lane*8);
      f32x4 d0 = __builtin_amdgcn_mfma_f32_16x16x32_bf16(p0, bq, (f32x4)0.f, 0,0,0);
      f32x4 d1 = __builtin_amdgcn_mfma_f32_16x16x32_bf16(p1, bq, (f32x4)0.f, 0,0,0);
      f32x4 d2 = __builtin_amdgcn_mfma_f32_16x16x32_bf16(p2, bq, (f32x4)0.f, 0,0,0);
      f32x4 d3 = __builtin_amdgcn_mfma_f32_16x16x32_bf16(p3, bq, (f32x4)0.f, 0,0,0);
      #pragma unroll
      for (int r=0; r<4; r++){
        float dx = d0[r];
        float t0=fminf(a0,dx), t1=__builtin_amdgcn_fmed3f(a0,a1,dx), t2=__builtin_amdgcn_fmed3f(a1,a2,dx);
        a0=t0; a1=t1; a2=t2;
        float dy = d1[r];
        float s0=fminf(c0,dy), s1=__builtin_amdgcn_fmed3f(c0,c1,dy), s2=__builtin_amdgcn_fmed3f(c1,c2,dy);
        c0=s0; c1=s1; c2=s2;
        float dz = d2[r];
        float u0=fminf(e0,dz), u1=__builtin_amdgcn_fmed3f(e0,e1,dz), u2=__builtin_amdgcn_fmed3f(e1,e2,dz);
        e0=u0; e1=u1; e2=u2;
        float dw = d3[r];
        float v0=fminf(g0,dw), v1=__builtin_amdgcn_fmed3f(g0,g1,dw), v2=__builtin_amdgcn_fmed3f(g1,g2,dw);
        g0=v0; g1=v1; g2=v2;
      }
    }
    __syncthreads();   // chunk fully consumed before restage
  }
  { // merge chains c,e,g into a (multiset union, keep 3 smallest)
    float dv9[9] = {c0,c1,c2, e0,e1,e2, g0,g1,g2};
    #pragma unroll
    for (int e=0; e<9; e++){
      float dx = dv9[e];
      float t0=fminf(a0,dx), t1=__builtin_amdgcn_fmed3f(a0,a1,dx), t2=__builtin_amdgcn_fmed3f(a1,a2,dx);
      a0=t0; a1=t1; a2=t2;
    }
  }
  #pragma unroll
  for (int st=16; st<64; st<<=1){   // merge across the 4 quad-lanes of each query
    float o0=__shfl_xor(a0,st,64), o1=__shfl_xor(a1,st,64), o2=__shfl_xor(a2,st,64);
    float dv3[3] = {o0,o1,o2};
    #pragma unroll
    for (int e=0; e<3; e++){
      float dx = dv3[e];
      float t0=fminf(a0,dx), t1=__builtin_amdgcn_fmed3f(a0,a1,dx), t2=__builtin_amdgcn_fmed3f(a1,a2,dx);
      a0=t0; a1=t1; a2=t2;
    }
  }
  float TT = a2 + 2.f*delta;
  // ---- pass 2: collect candidate indices (restaged chunks) ----
  int lq = wave*16 + ln;
  for (int ch=0; ch<4; ch++){
    #pragma unroll
    for (int i=0;i<8;i++)
      gl_lds16(Pfb + ch*16384 + i*2048 + wave*512 + lane*8, PB + i*2048 + wave*512);
    __syncthreads();
    for (int j=0; j<32; j++){
      short8 ap = *(const short8*)(PB + j*512 + lane*8);
      f32x4 dv = __builtin_amdgcn_mfma_f32_16x16x32_bf16(ap, bq, (f32x4)0.f, 0,0,0);
      if (__builtin_expect(dv[0]<=TT || dv[1]<=TT || dv[2]<=TT || dv[3]<=TT, 0)){
        #pragma unroll
        for (int r=0; r<4; r++){
          if (dv[r] <= TT){
            int m = (ch*32+j)*16 + quad*4 + r;
            int ix = atomicAdd(&lcount[lq], 1);
            if (ix < LCAP) lists[lq*LCAP + ix] = m;
          }
        }
      }
    }
    __syncthreads();
  }
  // ---- final: exact distances on the candidate list, stable lex top-3 ----
  if (quad == 0){
    int pid = blockIdx.x*64 + wave*16 + ln;
    size_t uo = ((size_t)b*N_ + pid)*3;
    float ux=ldf(unknown,uo,f), uy=ldf(unknown,uo+1,f), uz=ldf(unknown,uo+2,f);
    float x2 = __fadd_rn(__fadd_rn(__fmul_rn(ux,ux), __fmul_rn(uy,uy)), __fmul_rn(uz,uz));
    // pre-doubled coords: fl(2a*b)=2*fl(a*b), fl(2s+2t)=2*fl(s+t) -> bit-exact vs reference
    float u2x=ux+ux, u2y=uy+uy, u2z=uz+uz;
    float f0v=3.4e38f, f1v=3.4e38f, f2v=3.4e38f;
    int i0=0x7fffffff, i1=0x7fffffff, i2=0x7fffffff;
    int cnt = lcount[lq];
    int lim = (cnt <= LCAP) ? cnt : 0;
    for (int ii=0; ii<lim; ii++){
      int m = lists[lq*LCAP + ii];
      size_t o = ((size_t)b*M_ + m)*3;
      float kx=ldf(known,o,f), ky=ldf(known,o+1,f), kz=ldf(known,o+2,f);
      float y2 = __fadd_rn(__fadd_rn(__fmul_rn(kx,kx), __fmul_rn(ky,ky)), __fmul_rn(kz,kz));
      float dot2 = __fadd_rn(__fadd_rn(__fmul_rn(u2x,kx), __fmul_rn(u2y,ky)), __fmul_rn(u2z,kz));
      float dd = __fadd_rn(__fsub_rn(x2, dot2), y2);
      bool lt0 = (dd < f0v) || (dd == f0v && m < i0);
      bool lt1 = (dd < f1v) || (dd == f1v && m < i1);
      bool lt2 = (dd < f2v) || (dd == f2v && m < i2);
      if (lt0){ f2v=f1v;i2=i1; f1v=f0v;i1=i0; f0v=dd;i0=m; }
      else if (lt1){ f2v=f1v;i2=i1; f1v=dd;i1=m; }
      else if (lt2){ f2v=dd; i2=m; }
    }
    if (cnt > LCAP){  // overflow fallback: exact full scan (never on sane data)
      for (int m=0; m<M_; m++){
        size_t o = ((size_t)b*M_ + m)*3;
        float kx=ldf(known,o,f), ky=ldf(known,o+1,f), kz=ldf(known,o+2,f);
        float y2 = __fadd_rn(__fadd_rn(__fmul_rn(kx,kx), __fmul_rn(ky,ky)), __fmul_rn(kz,kz));
        float dot2 = __fadd_rn(__fadd_rn(__fmul_rn(u2x,kx), __fmul_rn(u2y,ky)), __fmul_rn(u2z,kz));
        float dd = __fadd_rn(__fsub_rn(x2, dot2), y2);
        bool lt0 = (dd < f0v) || (dd == f0v && m < i0);
        bool lt1 = (dd < f1v) || (dd == f1v && m < i1);
        bool lt2 = (dd < f2v) || (dd == f2v && m < i2);
        if (lt0){ f2v=f1v;i2=i1; f1v=f0v;i1=i0; f0v=dd;i0=m; }
        else if (lt1){ f2v=f1v;i2=i1; f1v=dd;i1=m; }
        else if (lt2){ f2v=dd; i2=m; }
      }
    }
    float da = __fsqrt_rn(fmaxf(f0v,1e-12f));
    float db = __fsqrt_rn(fmaxf(f1v,1e-12f));
    float dc = __fsqrt_rn(fmaxf(f2v,1e-12f));
    float r0 = __fdiv_rn(1.f, __fadd_rn(da,1e-8f));
    float r1 = __fdiv_rn(1.f, __fadd_rn(db,1e-8f));
    float r2 = __fdiv_rn(1.f, __fadd_rn(dc,1e-8f));
    float rs = __fadd_rn(__fadd_rn(r0,r1),r2);
    size_t o = ((size_t)b*N_ + pid)*3;
    idx3[o]=i0; idx3[o+1]=i1; idx3[o+2]=i2;
    w3[o]=__fdiv_rn(r0,rs); w3[o+1]=__fdiv_rn(r1,rs); w3[o+2]=__fdiv_rn(r2,rs);
  }
}

// ---------------- K2: three_interpolate -> Ft[:, :, 0:256] (point-major) ----------------
__global__ __launch_bounds__(256) void k2_interp(
    const void* kf, const int* __restrict__ idx3,
    const float* __restrict__ w3, const int* __restrict__ flagp, u16* __restrict__ Ft){
  __shared__ u16 Ls[M_*8]; // [i][c], 32KB
  int ct = blockIdx.x;  // 0..31 (channel tile of 8)
  int rg = blockIdx.y;  // 0..3 (rep group)
  int b = blockIdx.z, t = threadIdx.x;
  int f = flagp[0];
  for (int cp=0; cp<4; cp++){
    int c0 = ct*8 + cp*2;
    size_t base0 = ((size_t)b*DD + c0)*M_;
    size_t base1 = base0 + M_;
    for (int i=t; i<M_; i+=256){
      float f0 = ldf(kf, base0+i, f);
      float f1 = ldf(kf, base1+i, f);
      u32 w = (u32)f2bf(f0) | ((u32)f2bf(f1)<<16);
      *(u32*)(Ls + i*8 + cp*2) = w;
    }
  }
  __syncthreads();
  for (int rep=rg*8; rep<rg*8+8; rep++){
    int pid = rep*256 + t;
    size_t o3 = ((size_t)b*N_ + pid)*3;
    int ia = idx3[o3], ib = idx3[o3+1], ic = idx3[o3+2];
    float wa = w3[o3], wb = w3[o3+1], wc = w3[o3+2];
    short8 va = *(const short8*)(Ls + ia*8);
    short8 vb = *(const short8*)(Ls + ib*8);
    short8 vc = *(const short8*)(Ls + ic*8);
    u32x4 pk;
    #pragma unroll
    for (int cq=0; cq<4; cq++){
      float fa0 = bf2f((u16)va[cq*2]),   fb0 = bf2f((u16)vb[cq*2]),   fc0 = bf2f((u16)vc[cq*2]);
      float fa1 = bf2f((u16)va[cq*2+1]), fb1 = bf2f((u16)vb[cq*2+1]), fc1 = bf2f((u16)vc[cq*2+1]);
      float v0 = fmaf(wc, fc0, fmaf(wb, fb0, wa*fa0));
      float v1 = fmaf(wc, fc1, fmaf(wb, fb1, wa*fa1));
      pk[cq] = (u32)f2bf(v0) | ((u32)f2bf(v1)<<16);
    }
    *(u32x4*)(Ft + ((size_t)b*N_ + pid)*512 + ct*8) = pk;
  }
}

// ---------------- K2b: transpose unknow_feats -> Ft[:, :, 256:512] ----------------
__global__ __launch_bounds__(256) void k2b_transpose_uf(
    const void* uf, const int* __restrict__ flagp, u16* __restrict__ Ft){
  __shared__ u16 Ls[64*72];
  int bx = blockIdx.x, cy = blockIdx.y, b = blockIdx.z, t = threadIdx.x;
  int f = flagp[0];
  {
    int n = t & 63, cg = t >> 6;
    for (int i=0; i<16; i++){
      int c = cg*16 + i;
      Ls[n*72 + c] = f2bf(ldf(uf, ((size_t)b*DD + cy*64 + c)*N_ + bx*64 + n, f));
    }
  }
  __syncthreads();
  int nl = t>>2, cc = t&3;
  u16* dst = Ft + ((size_t)b*N_ + bx*64 + nl)*512 + 256 + cy*64 + cc*16;
  *(u32x4*)dst     = *(const u32x4*)(Ls + nl*72 + cc*16);
  *(u32x4*)(dst+8) = *(const u32x4*)(Ls + nl*72 + cc*16 + 8);
}

// ---------------- K3/K4: MFMA GEMM, BK=64, global_load_lds + XOR-swizzled LDS ----------------
__global__ __launch_bounds__(256) void gemm_bn_relu(
    const u16* __restrict__ W, const u16* __restrict__ Fin,
    const float* __restrict__ consts, int sc_off, int sh_off,
    u16* __restrict__ Out, int K){
  __shared__ u16 SM[17408]; // As(8192)+Bs(8192) u16 in K-loop; Cs(128x136) in epilogue
  u16* As = SM; u16* Bs = SM + 8192;
  int b = blockIdx.z, ot = blockIdx.y*128, nt = blockIdx.x*128;
  int t = threadIdx.x, wave = t>>6, lane = t&63, ln = lane&15, quad = lane>>4;
  int wo = (wave&1)*64, wn = (wave>>1)*64;
  f32x4 acc[4][4];
  #pragma unroll
  for (int i=0;i<4;i++)
    #pragma unroll
    for (int j=0;j<4;j++) acc[i][j] = (f32x4)0.f;
  const u16* Wp = W + (size_t)ot*K;
  const u16* Fp = Fin + ((size_t)b*N_ + nt)*K;
  for (int kk=0; kk<K; kk+=64){
    #pragma unroll
    for (int i=0;i<4;i++){
      int c = wave*256 + i*64 + lane;          // chunk slot 0..1023
      int r = c>>3, k8 = (c&7) ^ (r&7);
      const u16* gA = Wp + (size_t)r*K + kk + k8*8;
      const u16* gB = Fp + (size_t)r*K + kk + k8*8;
      gl_lds16(gA, As + (size_t)(wave*256 + i*64)*8);
      gl_lds16(gB, Bs + (size_t)(wave*256 + i*64)*8);
    }
    __syncthreads();
    #pragma unroll
    for (int kh=0; kh<2; kh++){
      short8 af[4], bfr[4];
      #pragma unroll
      for (int i=0;i<4;i++){
        int R = wo + i*16 + ln, C = kh*4 + quad;
        af[i] = *(const short8*)(As + (size_t)(R*8 + (C^(R&7)))*8);
      }
      #pragma unroll
      for (int j=0;j<4;j++){
        int R = wn + j*16 + ln, C = kh*4 + quad;
        bfr[j] = *(const short8*)(Bs + (size_t)(R*8 + (C^(R&7)))*8);
      }
      #pragma unroll
      for (int i=0;i<4;i++)
        #pragma unroll
        for (int j=0;j<4;j++)
          acc[i][j] = __builtin_amdgcn_mfma_f32_16x16x32_bf16(af[i], bfr[j], acc[i][j], 0,0,0);
    }
    __syncthreads();
  }
  u16* Cs = SM; // stride 136
  #pragma unroll
  for (int i=0;i<4;i++){
    #pragma unroll
    for (int r=0;r<4;r++){
      int ol = wo + i*16 + quad*4 + r;
      float sc = consts[sc_off + ot + ol], sh = consts[sh_off + ot + ol];
      #pragma unroll
      for (int j=0;j<4;j++){
        float v = fmaxf(fmaf(acc[i][j][r], sc, sh), 0.f);
        Cs[(wn + j*16 + ln)*136 + ol] = f2bf(v);
      }
    }
  }
  __syncthreads();
  int nl = t>>1, half = t&1;
  u16* dst = Out + ((size_t)b*N_ + nt + nl)*256 + ot + half*64;
  const u16* srcr = Cs + nl*136 + half*64;
  #pragma unroll
  for (int c=0;c<8;c++)
    *(u32x4*)(dst + c*8) = *(const u32x4*)(srcr + c*8);
}

// ---------------- K5: encoding partials ----------------
__global__ __launch_bounds__(256, 6) void k5_enc_partial(
    const u16* __restrict__ X, const u16* __restrict__ cw,
    const float* __restrict__ consts, float* __restrict__ Epart,
    float* __restrict__ Asum){
  __shared__ u16 Xs[64*256];      // 32KB, swizzled
  __shared__ float A_lds[64*32];  // 8KB
  int g = blockIdx.x, b = blockIdx.y, t = threadIdx.x;
  int wave = t>>6, lane = t&63, ln = lane&15, quad = lane>>4;
  int ka = lane>>1, h = lane&1;          // accumulation roles: k index, d-half
  int dbase = wave*64 + h*32;            // 32 consecutive d per thread
  float c2v0 = consts[C2OFF + ln], c2v1 = consts[C2OFF + 16 + ln];
  float sv0  = consts[SOFF + ln],  sv1  = consts[SOFF + 16 + ln];
  int n0 = g*64;
  const u16* Xp = X + ((size_t)b*N_ + n0)*256;
  #pragma unroll
  for (int i=0;i<8;i++){
    int ch = t + i*256;
    int r = ch>>5, cc = ch&31;
    *(u32x4*)(Xs + r*256 + ((cc ^ (r&15))<<3)) = *(const u32x4*)(Xp + r*256 + cc*8);
  }
  __syncthreads();
  float xnf;
  {
    int row = t>>2, part = t&3;
    float s = 0.f;
    #pragma unroll
    for (int j=0;j<8;j++){
      int cc = part*8 + j;
      short8 xv = *(const short8*)(Xs + row*256 + ((cc ^ (row&15))<<3));
      #pragma unroll
      for (int q=0;q<8;q++){ float x = bf2f((u16)xv[q]); s = fmaf(x,x,s); }
    }
    s += __shfl_xor(s,1,64);
    s += __shfl_xor(s,2,64);
    xnf = s;
  }
  f32x4 pj0 = (f32x4)0.f, pj1 = (f32x4)0.f;
  {
    int row = wave*16 + ln;
    #pragma unroll
    for (int kk=0; kk<256; kk+=32){
      int cc = (kk>>3) + quad;
      short8 a   = *(const short8*)(Xs + row*256 + ((cc ^ (row&15))<<3));
      short8 bf0 = *(const short8*)(cw + (size_t)ln*256 + kk + quad*8);
      short8 bf1 = *(const short8*)(cw + (size_t)(16+ln)*256 + kk + quad*8);
      pj0 = __builtin_amdgcn_mfma_f32_16x16x32_bf16(a, bf0, pj0, 0,0,0);
      pj1 = __builtin_amdgcn_mfma_f32_16x16x32_bf16(a, bf1, pj1, 0,0,0);
    }
  }
  #pragma unroll
  for (int r=0;r<4;r++){
    int nl = wave*16 + quad*4 + r;
    float xv = __shfl(xnf, (quad*4 + r)*4, 64);   // producer lane is in this wave
    float v0 = sv0 * __fadd_rn(__fsub_rn(xv, __fmul_rn(2.f,pj0[r])), c2v0);
    float v1 = sv1 * __fadd_rn(__fsub_rn(xv, __fmul_rn(2.f,pj1[r])), c2v1);
    float mx = fmaxf(v0,v1);
    #pragma unroll
    for (int d=1; d<16; d<<=1) mx = fmaxf(mx, __shfl_xor(mx, d, 64));
    float e0 = __expf(v0-mx), e1 = __expf(v1-mx);
    float es = e0+e1;
    #pragma unroll
    for (int d=1; d<16; d<<=1) es += __shfl_xor(es, d, 64);
    float inv = 1.f/es;
    A_lds[nl*32 + ln]      = e0*inv;
    A_lds[nl*32 + 16 + ln] = e1*inv;
  }
  __syncthreads();
  float accE[32];
  #pragma unroll
  for (int p=0;p<32;p++) accE[p]=0.f;
  float asum = 0.f;
  int cbase = wave*8 + h*4;
  #pragma unroll 2
  for (int n=0; n<64; n++){
    float a = A_lds[n*32 + ka];        // 32 dwords, 2-way broadcast, conflict-free
    asum += a;
    const u16* xr = Xs + n*256;
    int sw = (n&15)<<3;
    #pragma unroll
    for (int p8=0; p8<4; p8++){
      u32x4 xv = *(const u32x4*)(xr + ((((cbase + p8)<<3) ^ sw)));
      #pragma unroll
      for (int q=0; q<4; q++){
        u32 w = xv[q];
        float lo = __uint_as_float(w<<16);
        float hi = __uint_as_float(w & 0xffff0000u);
        accE[p8*8 + q*2]   = fmaf(a, lo, accE[p8*8 + q*2]);
        accE[p8*8 + q*2+1] = fmaf(a, hi, accE[p8*8 + q*2+1]);
      }
    }
  }
  int slab = b*128 + g;
  float* Ed = Epart + (size_t)slab*8192 + (size_t)ka*256 + dbase;
  #pragma unroll
  for (int p=0;p<32;p++) Ed[p] = accE[p];
  if (wave==0 && h==0) Asum[slab*32 + ka] = asum;
}

// ---------------- K5b: reduce slabs, subtract asum*cw, relu ----------------
__global__ __launch_bounds__(256) void k5b_reduce(
    const float* __restrict__ Epart, const float* __restrict__ Asum,
    const u16* __restrict__ cw, float* __restrict__ Erelu){
  int id = blockIdx.x*256 + threadIdx.x;
  int d = id & 255, k = (id>>8)&31, b = id>>13;
  float s = 0.f, as = 0.f;
  for (int sl=0; sl<128; sl++){
    s  += Epart[((size_t)(b*128+sl))*8192 + (size_t)k*256 + d];
    as += Asum[(b*128+sl)*32 + k];
  }
  float cv = bf2f(cw[k*256+d]);
  Erelu[(size_t)b*8192 + k*256 + d] = fmaxf(s - as*cv, 0.f);
}

// ---------------- K6a: per-batch L2 norm ----------------
__global__ __launch_bounds__(256) void k6a_norm(
    const float* __restrict__ Erelu, float* __restrict__ consts){
  __shared__ float red[256];
  int b = blockIdx.x, t = threadIdx.x;
  float s = 0.f;
  for (int i=0;i<32;i++){ float e = Erelu[(size_t)b*8192 + i*256 + t]; s = fmaf(e,e,s); }
  red[t] = s; __syncthreads();
  for (int w=128; w>0; w>>=1){ if (t<w) red[t] += red[t+w]; __syncthreads(); }
  if (t==0) consts[RNOFF + b] = 1.f/fmaxf(__fsqrt_rn(red[0]), 1e-12f);
}

// ---------------- K6b: linear partial dots ----------------
__global__ __launch_bounds__(256) void k6b_partial(
    const float* __restrict__ Erelu, const void* lw, const int* __restrict__ flagp,
    float* __restrict__ partials){
  __shared__ float Er[256];
  int kc = blockIdx.x, b = blockIdx.y, t = threadIdx.x;
  int f = flagp[0];
  Er[t] = Erelu[(size_t)b*8192 + kc*256 + t];
  __syncthreads();
  float s = 0.f;
  if (f){
    const float* lwp = (const float*)lw + (size_t)t*8192 + kc*256;
    for (int p=0; p<256; p+=4){
      f32x4 v = *(const f32x4*)(lwp + p);
      #pragma unroll
      for (int q=0;q<4;q++) s = fmaf(Er[p+q], v[q], s);
    }
  } else {
    const u16* lwp = (const u16*)lw + (size_t)t*8192 + kc*256;
    for (int p=0; p<256; p+=8){
      u32x4 v = *(const u32x4*)(lwp + p);
      #pragma unroll
      for (int q=0;q<4;q++){
        u32 w = v[q];
        s = fmaf(Er[p+q*2],   __uint_as_float(w<<16), s);
        s = fmaf(Er[p+q*2+1], __uint_as_float(w & 0xffff0000u), s);
      }
    }
  }
  partials[((size_t)b*32 + kc)*256 + t] = s;
}

// ---------------- K6c: ctx = sigmoid(rnorm*dot + bias) ----------------
__global__ __launch_bounds__(256) void k6c_ctx(
    const float* __restrict__ partials, const float* __restrict__ consts,
    const void* lb, const int* __restrict__ flagp, float* __restrict__ ctx){
  int b = blockIdx.x, t = threadIdx.x;
  int f = flagp[0];
  float s = 0.f;
  for (int kc=0; kc<32; kc++) s += partials[((size_t)b*32+kc)*256 + t];
  float x = fmaf(consts[RNOFF+b], s, ldf(lb,t,f));
  ctx[b*256 + t] = 1.f/(1.f + __expf(-x));
}

// ---------------- K7: out[b][o][n] = ht[b][n][o] * ctx[b][o] ----------------
__global__ __launch_bounds__(256) void k7_out(
    const u16* __restrict__ ht, const float* __restrict__ ctx,
    const int* __restrict__ flagp, void* out){
  __shared__ u16 Ls[64*72];
  int bx = blockIdx.x, oy = blockIdx.y, b = blockIdx.z, t = threadIdx.x;
  int f = flagp[0];
  {
    int nl = t>>2, oc = t&3;
    const u16* src = ht + ((size_t)b*N_ + bx*64 + nl)*256 + oy*64 + oc*16;
    *(u32x4*)(Ls + nl*72 + oc*16)     = *(const u32x4*)src;
    *(u32x4*)(Ls + nl*72 + oc*16 + 8) = *(const u32x4*)(src + 8);
  }
  __syncthreads();
  int ol = t>>2, nc = t&3;
  float cv = ctx[b*256 + oy*64 + ol];
  size_t dstoff = ((size_t)b*DD + oy*64 + ol)*N_ + bx*64 + nc*16;
  if (f){
    float* dst = (float*)out + dstoff;
    #pragma unroll
    for (int wq=0; wq<4; wq++){
      f32x4 v;
      #pragma unroll
      for (int q=0;q<4;q++) v[q] = bf2f(Ls[(nc*16 + wq*4 + q)*72 + ol]) * cv;
      *(f32x4*)(dst + wq*4) = v;
    }
  } else {
    u32 words[8];
    #pragma unroll
    for (int wq=0; wq<8; wq++){
      float v0 = bf2f(Ls[(nc*16 + wq*2)*72 + ol]) * cv;
      float v1 = bf2f(Ls[(nc*16 + wq*2+1)*72 + ol]) * cv;
      words[wq] = (u32)f2bf(v0) | ((u32)f2bf(v1)<<16);
    }
    u16* dst = (u16*)out + dstoff;
    u32x4 w0 = {words[0],words[1],words[2],words[3]};
    u32x4 w1 = {words[4],words[5],words[6],words[7]};
    *(u32x4*)dst     = w0;
    *(u32x4*)(dst+8) = w1;
  }
}

extern "C" void kernel_launch(void* const* d_in, const int* in_sizes, int n_in,
                              void* d_out, int out_size, void* d_ws, size_t ws_size,
                              hipStream_t stream){
  const void* unknown = d_in[0];
  const void* known   = d_in[1];
  const void* uf      = d_in[2];
  const void* kf      = d_in[3];
  const void* w1      = d_in[4];
  const void* cb1     = d_in[5];
  const void* g1      = d_in[6];
  const void* be1     = d_in[7];
  const void* m1      = d_in[8];
  const void* v1      = d_in[9];
  const void* w2      = d_in[10];
  const void* cb2     = d_in[11];
  const void* g2      = d_in[12];
  const void* be2     = d_in[13];
  const void* m2      = d_in[14];
  const void* v2      = d_in[15];
  const void* cw      = d_in[16];
  const void* es      = d_in[17];
  const void* lw      = d_in[18];
  const void* lb      = d_in[19];

  char* ws = (char*)d_ws;
  int*   idx3  = (int*)(ws + OFF_IDX3);
  float* w3    = (float*)(ws + OFF_W3);
  u16*   Ft    = (u16*)(ws + OFF_FT);
  u16*   ht    = Ft;                       // alias: Ft dead after GEMM1 consumes it
  u16*   h1t   = (u16*)(ws + OFF_H1T);
  float* Epart = (float*)(ws + OFF_H1T);   // alias: h1t dead after GEMM2
  float* Asum  = (float*)(ws + OFF_IDX3);  // alias: idx3 dead after k2_interp
  float* Erelu    = (float*)(ws + OFF_ERELU);
  float* partials = (float*)(ws + OFF_PART);
  float* consts   = (float*)(ws + OFF_CONSTS);
  float* ctx      = (float*)(ws + OFF_CTX);
  u16*   W1d   = (u16*)(ws + OFF_W1D);
  u16*   W2d   = (u16*)(ws + OFF_W2D);
  u16*   CWd   = (u16*)(ws + OFF_CWD);
  int*   flagp = (int*)(ws + OFF_FLAG);
  u32*   cmaxp = (u32*)(ws + OFF_FLAG) + 1;
  u16*   Qf    = (u16*)(ws + OFF_QF);      // alias: Ft region, dead until k2
  u16*   Pf    = (u16*)(ws + OFF_PF);

  k_detect<<<1, 256, 0, stream>>>(v1, flagp);
  k_convert<<<800, 256, 0, stream>>>(w1, w2, cw, flagp, W1d, W2d, CWd);
  k_frag<<<320, 256, 0, stream>>>(unknown, known, flagp, Qf, Pf, cmaxp);
  k0_setup<<<1, 256, 0, stream>>>(cb1,g1,be1,m1,v1, cb2,g2,be2,m2,v2, CWd, es, flagp, consts);
  k1_three_nn<<<dim3(128,8), 256, 0, stream>>>(unknown, known, flagp, Qf, Pf, cmaxp, idx3, w3);
  k2_interp<<<dim3(32,4,8), 256, 0, stream>>>(kf, idx3, w3, flagp, Ft);
  k2b_transpose_uf<<<dim3(128,4,8), 256, 0, stream>>>(uf, flagp, Ft);
  gemm_bn_relu<<<dim3(64,2,8), 256, 0, stream>>>(W1d, Ft,  consts, SC1, SH1, h1t, 512);
  gemm_bn_relu<<<dim3(64,2,8), 256, 0, stream>>>(W2d, h1t, consts, SC2, SH2, ht,  256);
  k5_enc_partial<<<dim3(128,8), 256, 0, stream>>>(ht, CWd, consts, Epart, Asum);
  k5b_reduce<<<256, 256, 0, stream>>>(Epart, Asum, CWd, Erelu);
  k6a_norm<<<8, 256, 0, stream>>>(Erelu, consts);
  k6b_partial<<<dim3(32,8), 256, 0, stream>>>(Erelu, lw, flagp, partials);
  k6c_ctx<<<8, 256, 0, stream>>>(partials, consts, lb, flagp, ctx);
  k7_out<<<dim3(128,4,8), 256, 0, stream>>>(ht, ctx, flagp, d_out);
}